// Round 9
// baseline (318.282 us; speedup 1.0000x reference)
//
#include <hip/hip_runtime.h>
#include <hip/hip_bf16.h>

// TransformerLayer on MI355X (gfx950). Round 9:
//  attn_fused v4 — occupancy attack: 40KB LDS + <=128 VGPR -> 4 blocks/CU
//  (16 waves/CU vs 8 in R6/R8). TK=32, K dbuf 2x16KB, P dbuf 2x4KB,
//  per-wave Q rows halved (qf 32 VGPR). Snake qt mapping: each CU's 4
//  resident blocks sum to equal causal work. Keep: pre-swizzled K staging,
//  1 barrier/tile, counted vmcnt(8), V direct->reg, reg->f32 P dump.
//  GEMM stack unchanged (R5+ passing config).

typedef __bf16 bf16_t;
typedef __bf16 bf16x8 __attribute__((ext_vector_type(8)));
typedef __bf16 bf16x4 __attribute__((ext_vector_type(4)));
typedef float  f32x4  __attribute__((ext_vector_type(4)));

#define DEV __device__ __forceinline__

DEV f32x4 mfma16(bf16x8 a, bf16x8 b, f32x4 c) {
  return __builtin_amdgcn_mfma_f32_16x16x32_bf16(a, b, c, 0, 0, 0);
}

DEV void gload16(const void* g, void* l) {
  __builtin_amdgcn_global_load_lds(
      (const __attribute__((address_space(1))) unsigned int*)g,
      (__attribute__((address_space(3))) unsigned int*)l, 16, 0, 0);
}

// ---------------- fused LN1 + weight cvt (grid 1024 + 2560) ----------------
__global__ __launch_bounds__(256) void k1_lncvt(
    const float* __restrict__ x, const float* __restrict__ g, const float* __restrict__ bta,
    float* __restrict__ of, bf16_t* __restrict__ ob,
    const float* __restrict__ s0, const float* __restrict__ s1,
    const float* __restrict__ s2, const float* __restrict__ s3,
    const float* __restrict__ s4, const float* __restrict__ s5,
    bf16_t* __restrict__ d0, bf16_t* __restrict__ d1, bf16_t* __restrict__ d2,
    bf16_t* __restrict__ d3, bf16_t* __restrict__ d4, bf16_t* __restrict__ d5) {
  int bid = blockIdx.x;
  if (bid < 1024) {
    int row = bid * 4 + (threadIdx.x >> 6);
    int l = threadIdx.x & 63;
    const float4 v = *(const float4*)(x + (size_t)row * 256 + l * 4);
    float s  = v.x + v.y + v.z + v.w;
    float s2 = v.x*v.x + v.y*v.y + v.z*v.z + v.w*v.w;
#pragma unroll
    for (int o = 1; o < 64; o <<= 1) { s += __shfl_xor(s, o, 64); s2 += __shfl_xor(s2, o, 64); }
    float m   = s * (1.f/256.f);
    float var = s2 * (1.f/256.f) - m * m;
    float rs  = rsqrtf(var + 1e-9f);
    const float4 gv = *(const float4*)(g   + l * 4);
    const float4 bv = *(const float4*)(bta + l * 4);
    float4 y;
    y.x = (v.x - m) * rs * gv.x + bv.x;
    y.y = (v.y - m) * rs * gv.y + bv.y;
    y.z = (v.z - m) * rs * gv.z + bv.z;
    y.w = (v.w - m) * rs * gv.w + bv.w;
    *(float4*)(of + (size_t)row * 256 + l * 4) = y;
    bf16x4 yb = { (bf16_t)y.x, (bf16_t)y.y, (bf16_t)y.z, (bf16_t)y.w };
    *(bf16x4*)(ob + (size_t)row * 256 + l * 4) = yb;
  } else {
    int i = (bid - 1024) * 256 + threadIdx.x;
    const float* s; bf16_t* d; int off;
    if      (i < 131072) { s = s0; d = d0; off = i; }
    else if (i < 262144) { s = s1; d = d1; off = i - 131072; }
    else if (i < 393216) { s = s2; d = d2; off = i - 262144; }
    else if (i < 524288) { s = s3; d = d3; off = i - 393216; }
    else if (i < 589824) { s = s4; d = d4; off = i - 524288; }
    else                 { s = s5; d = d5; off = i - 589824; }
    float4 v = ((const float4*)s)[off];
    bf16x4 o = { (bf16_t)v.x, (bf16_t)v.y, (bf16_t)v.z, (bf16_t)v.w };
    ((bf16x4*)d)[off] = o;
  }
}

// ---------------- 2-phase double-buffered 128x128 GEMM core ----------------
DEV void gemm_core(const bf16_t* __restrict__ A, const bf16_t* __restrict__ W,
                   int lda, int row0, int col0, int k0, int kiters,
                   char* Asb, char* Bsb, f32x4 (&acc)[4][4]) {
  int tid = threadIdx.x, w = tid >> 6, l = tid & 63, l15 = l & 15, lhi = l >> 4;
  int wr = (w >> 1) * 64, wc = (w & 1) * 64;

#define STAGE(buf, kk) do {                                                   \
    char* Ad = Asb + (buf) * 8192 + w * 1024;                                 \
    char* Bd = Bsb + (buf) * 8192 + w * 1024;                                 \
    _Pragma("unroll")                                                         \
    for (int j = 0; j < 2; ++j) {                                             \
      int idx = (j * 256 + tid) * 8; int r = idx >> 5, c = idx & 31;          \
      gload16(A + (size_t)(row0 + r) * lda + (kk) + c, Ad + j * 4096);        \
      gload16(W + (size_t)(col0 + r) * lda + (kk) + c, Bd + j * 4096);        \
    } } while (0)

  STAGE(0, k0);
  for (int t = 0; t < kiters; ++t) {
    int cur = t & 1;
    if (t + 1 < kiters) {
      STAGE(cur ^ 1, k0 + (t + 1) * 32);
      asm volatile("s_waitcnt vmcnt(4)" ::: "memory");
    } else {
      asm volatile("s_waitcnt vmcnt(0)" ::: "memory");
    }
    __builtin_amdgcn_s_barrier();
    asm volatile("" ::: "memory");
    const bf16_t* As = (const bf16_t*)(Asb + cur * 8192);
    const bf16_t* Bs = (const bf16_t*)(Bsb + cur * 8192);
    bf16x8 af[4], bfr[4];
#pragma unroll
    for (int m = 0; m < 4; ++m)
      af[m] = *(const bf16x8*)(As + (wr + 16 * m + l15) * 32 + lhi * 8);
#pragma unroll
    for (int n = 0; n < 4; ++n)
      bfr[n] = *(const bf16x8*)(Bs + (wc + 16 * n + l15) * 32 + lhi * 8);
#pragma unroll
    for (int m = 0; m < 4; ++m)
#pragma unroll
      for (int n = 0; n < 4; ++n)
        acc[m][n] = mfma16(af[m], bfr[n], acc[m][n]);
    asm volatile("s_waitcnt lgkmcnt(0)" ::: "memory");
    __builtin_amdgcn_s_barrier();
  }
#undef STAGE
}

// ---------------- fused QKV: grid (48, 32); V writes V^T via LDS transpose ----------------
__global__ __launch_bounds__(256, 4) void gemm_qkv(
    const bf16_t* __restrict__ A,
    const bf16_t* __restrict__ W0, const bf16_t* __restrict__ W1, const bf16_t* __restrict__ W2,
    const float* __restrict__ b0, const float* __restrict__ b1, const float* __restrict__ b2,
    bf16_t* __restrict__ qo, bf16_t* __restrict__ ko, bf16_t* __restrict__ vto) {
  __shared__ char smem[34816];   // staging 32KB | V-transpose 128x136 bf16
  char* Asb = smem;
  char* Bsb = smem + 16384;
  int bx = blockIdx.x;
  int wsel = bx >> 4, cb = bx & 15;
  const bf16_t* W    = wsel == 0 ? W0 : (wsel == 1 ? W1 : W2);
  const float*  bias = wsel == 0 ? b0 : (wsel == 1 ? b1 : b2);
  int row0 = blockIdx.y * 128, col0 = cb * 128;
  f32x4 acc[4][4] = {};
  gemm_core(A, W, 256, row0, col0, 0, 8, Asb, Bsb, acc);

  int tid = threadIdx.x, w = tid >> 6, l = tid & 63, l15 = l & 15, lhi = l >> 4;
  int wr = (w >> 1) * 64, wc = (w & 1) * 64;

  if (wsel < 2) {
    bf16_t* out = wsel == 0 ? qo : ko;
#pragma unroll
    for (int m = 0; m < 4; ++m)
#pragma unroll
      for (int n = 0; n < 4; ++n)
#pragma unroll
        for (int j = 0; j < 4; ++j) {
          int row = row0 + wr + 16 * m + lhi * 4 + j;
          int col = col0 + wc + 16 * n + l15;
          float v = acc[m][n][j] + bias[col];
          out[((size_t)((row >> 11) * 8 + (col >> 8)) * 2048 + (row & 2047)) * 256 + (col & 255)] = (bf16_t)v;
        }
  } else {
    // V: transpose in LDS, write V^T (B,H,Dh,S)
    __syncthreads();   // full drain before overwriting staging LDS
    bf16_t* T = (bf16_t*)smem;   // [128 d][136 stride] bf16
#pragma unroll
    for (int m = 0; m < 4; ++m)
#pragma unroll
      for (int n = 0; n < 4; ++n) {
        int d = wc + 16 * n + l15;
        int s = wr + 16 * m + lhi * 4;
        bf16x4 v4;
#pragma unroll
        for (int j = 0; j < 4; ++j) v4[j] = (bf16_t)(acc[m][n][j] + bias[col0 + d]);
        *(bf16x4*)(T + d * 136 + s) = v4;
      }
    __syncthreads();
    int bh = ((row0 >> 11) << 3) + (col0 >> 8);
    int d0 = col0 & 255, s0g = row0 & 2047;
#pragma unroll
    for (int p = 0; p < 8; ++p) {
      int idx = p * 256 + tid;
      int d = idx >> 4, c = (idx & 15) * 8;
      bf16x8 v8 = *(const bf16x8*)(T + d * 136 + c);
      *(bf16x8*)(vto + ((size_t)bh * 256 + d0 + d) * 2048 + s0g + c) = v8;
    }
  }
}

// ---------------- split-K partial GEMM: N=256, grid (2, 32, 4) ----------------
__global__ __launch_bounds__(256, 4) void gemm_part(
    const bf16_t* __restrict__ A, const bf16_t* __restrict__ W,
    int lda, int ksub, float* __restrict__ parts) {
  __shared__ char Asb[2 * 8192];
  __shared__ char Bsb[2 * 8192];
  int z = blockIdx.z;
  int row0 = blockIdx.y * 128, col0 = blockIdx.x * 128;
  f32x4 acc[4][4] = {};
  gemm_core(A, W, lda, row0, col0, z * ksub, ksub >> 5, Asb, Bsb, acc);

  int tid = threadIdx.x, w = tid >> 6, l = tid & 63, l15 = l & 15, lhi = l >> 4;
  int wr = (w >> 1) * 64, wc = (w & 1) * 64;
  float* p = parts + (size_t)z * 1048576;
#pragma unroll
  for (int m = 0; m < 4; ++m)
#pragma unroll
    for (int n = 0; n < 4; ++n)
#pragma unroll
      for (int j = 0; j < 4; ++j) {
        int row = row0 + wr + 16 * m + lhi * 4 + j;
        int col = col0 + wc + 16 * n + l15;
        p[(size_t)row * 256 + col] = acc[m][n][j];
      }
}

// ---------------- reduce 4 partials + bias + residual (final out) ----------------
__global__ __launch_bounds__(256) void reduce4(
    const float* __restrict__ parts, const float* __restrict__ bias,
    const float* __restrict__ res, float* __restrict__ out) {
  int i = blockIdx.x * 256 + threadIdx.x;
  f32x4 s = *(const f32x4*)(parts + (size_t)i * 4);
  s += *(const f32x4*)(parts + 1048576 + (size_t)i * 4);
  s += *(const f32x4*)(parts + 2097152 + (size_t)i * 4);
  s += *(const f32x4*)(parts + 3145728 + (size_t)i * 4);
  s += *(const f32x4*)(res + (size_t)i * 4);
  s += *(const f32x4*)(bias + (i & 63) * 4);
  *(f32x4*)(out + (size_t)i * 4) = s;
}

// ---------------- fused dense-reduce + residual + LN2 ----------------
__global__ __launch_bounds__(256) void reduce_ln(
    const float* __restrict__ parts, const float* __restrict__ bias,
    const float* __restrict__ res, const float* __restrict__ g,
    const float* __restrict__ bta, float* __restrict__ x1o, bf16_t* __restrict__ mo) {
  int row = blockIdx.x * 4 + (threadIdx.x >> 6);
  int l = threadIdx.x & 63;
  size_t base = (size_t)row * 256 + l * 4;
  f32x4 s = *(const f32x4*)(parts + base);
  s += *(const f32x4*)(parts + 1048576 + base);
  s += *(const f32x4*)(parts + 2097152 + base);
  s += *(const f32x4*)(parts + 3145728 + base);
  s += *(const f32x4*)(res + base);
  s += *(const f32x4*)(bias + l * 4);
  *(f32x4*)(x1o + base) = s;
  float sm = s[0] + s[1] + s[2] + s[3];
  float s2 = s[0]*s[0] + s[1]*s[1] + s[2]*s[2] + s[3]*s[3];
#pragma unroll
  for (int o = 1; o < 64; o <<= 1) { sm += __shfl_xor(sm, o, 64); s2 += __shfl_xor(s2, o, 64); }
  float m   = sm * (1.f/256.f);
  float var = s2 * (1.f/256.f) - m * m;
  float rs  = rsqrtf(var + 1e-9f);
  const float4 gv = *(const float4*)(g   + l * 4);
  const float4 bv = *(const float4*)(bta + l * 4);
  bf16x4 yb;
  yb[0] = (bf16_t)((s[0] - m) * rs * gv.x + bv.x);
  yb[1] = (bf16_t)((s[1] - m) * rs * gv.y + bv.y);
  yb[2] = (bf16_t)((s[2] - m) * rs * gv.z + bv.z);
  yb[3] = (bf16_t)((s[3] - m) * rs * gv.w + bv.w);
  *(bf16x4*)(mo + base) = yb;
}

// ---------------- FC1 with gelu ----------------
__global__ __launch_bounds__(256, 4) void gemm_fc1(
    const bf16_t* __restrict__ A, const bf16_t* __restrict__ W,
    const float* __restrict__ bias, bf16_t* __restrict__ out) {
  __shared__ char Asb[2 * 8192];
  __shared__ char Bsb[2 * 8192];
  int row0 = blockIdx.y * 128, col0 = blockIdx.x * 128;
  f32x4 acc[4][4] = {};
  gemm_core(A, W, 256, row0, col0, 0, 8, Asb, Bsb, acc);

  int tid = threadIdx.x, w = tid >> 6, l = tid & 63, l15 = l & 15, lhi = l >> 4;
  int wr = (w >> 1) * 64, wc = (w & 1) * 64;
#pragma unroll
  for (int m = 0; m < 4; ++m)
#pragma unroll
    for (int n = 0; n < 4; ++n)
#pragma unroll
      for (int j = 0; j < 4; ++j) {
        int row = row0 + wr + 16 * m + lhi * 4 + j;
        int col = col0 + wc + 16 * n + l15;
        float t = acc[m][n][j] + bias[col];
        float ge = 0.5f * t * (1.f + tanhf(0.7978845608f * t * (1.f + 0.044715f * t * t)));
        out[(size_t)row * 1024 + col] = (bf16_t)ge;
      }
}

// ---------------- fused attention v4: QBLK=32, TK=32, 40KB LDS, 4 blocks/CU --
// grid 1024: bh = bx&15; snake qt so each CU's 4 resident blocks have equal work
__global__ __launch_bounds__(256, 4) void attn_fused(
    const bf16_t* __restrict__ qg, const bf16_t* __restrict__ kg,
    const bf16_t* __restrict__ vt, float* __restrict__ pout,
    bf16_t* __restrict__ ctxo) {
  __shared__ __align__(16) char smem[40960];
  char* Ksh = smem;               // 2 x 16KB K dbuf (TK=32 x 256)
  char* Psh = smem + 32768;       // 2 x 4KB P dbuf (32 x 32 bf16)
  float* sl    = (float*)(smem + 32768);  // scratch, aliases Psh (used between passes)
  float* invsh = sl + 64;

  int bx = blockIdx.x;
  int bh = bx & 15;
  int r4 = bx >> 8, g4 = (bx >> 4) & 15;
  int tq = 16 * r4 + ((r4 & 1) ? (15 - g4) : g4);   // snake over [0,63]
  int qt = 63 - tq;
  int qbase = qt * 32;
  int nkt = qt + 1;               // TK=32 tiles covering k <= qbase+31

  int tid = threadIdx.x, w = tid >> 6, l = tid & 63;
  int l15 = l & 15, lhi = l >> 4;
  int wm = w >> 1, wn = w & 1;
  const bf16_t* Q = qg + (size_t)bh * 2048 * 256;
  const bf16_t* K = kg + (size_t)bh * 2048 * 256;
  const bf16_t* V = vt + (size_t)bh * 256 * 2048;

  // Q fragments: this wave's 16 rows [qbase + wm*16, +16)
  bf16x8 qf[8];
#pragma unroll
  for (int ks = 0; ks < 8; ++ks)
    qf[ks] = *(const bf16x8*)(Q + (size_t)(qbase + wm * 16 + l15) * 256 + ks * 32 + lhi * 8);

  // K stage TK=32: LDS linear dest, source pre-swizzled by ^((row&15)<<4)
#define KSTAGE(td_, ts_) do {                                                  \
    char* dst0 = Ksh + ((td_) & 1) * 16384 + w * 4096;                         \
    _Pragma("unroll")                                                          \
    for (int j5 = 0; j5 < 4; ++j5) {                                           \
      int idxb = w * 4096 + j5 * 1024 + (tid & 63) * 16;                       \
      int rr5 = idxb >> 9; int inner = idxb & 511;                             \
      int colb = inner ^ ((rr5 & 15) << 4);                                    \
      gload16(K + (size_t)((ts_) * 32 + rr5) * 256 + (colb >> 1), dst0 + j5 * 1024); \
    } } while (0)

  int krow = wn * 16 + l15;          // this lane's K row (QK B-operand)
  int ksw  = (krow & 15) << 4;

  // ================= pass A: masked exp rowsums =================
  KSTAGE(0, 0);
  asm volatile("s_waitcnt vmcnt(0)" ::: "memory");
  __builtin_amdgcn_s_barrier();

  float sums[4] = {};
  for (int t = 0; t < nkt; ++t) {
    int tn = (t + 1 < nkt) ? t + 1 : nkt - 1;
    KSTAGE(t + 1, tn);
    const char* Kb = Ksh + (t & 1) * 16384;
    f32x4 acc = {};
    __builtin_amdgcn_s_setprio(1);
#pragma unroll
    for (int ks = 0; ks < 8; ++ks) {
      bf16x8 kb = *(const bf16x8*)(Kb + krow * 512 + ((ks * 64 + lhi * 16) ^ ksw));
      acc = mfma16(qf[ks], kb, acc);
    }
    __builtin_amdgcn_s_setprio(0);
#pragma unroll
    for (int j = 0; j < 4; ++j) {
      int qr = qbase + wm * 16 + lhi * 4 + j;
      int kc = t * 32 + krow;
      sums[j] += (kc <= qr) ? __expf(acc[j] * 0.0625f) : 0.f;
    }
    asm volatile("s_waitcnt vmcnt(0)" ::: "memory");
    __builtin_amdgcn_s_barrier();
  }

#pragma unroll
  for (int j = 0; j < 4; ++j)
#pragma unroll
    for (int o = 1; o < 16; o <<= 1)
      sums[j] += __shfl_xor(sums[j], o, 64);
  if (l15 == 0)
#pragma unroll
    for (int j = 0; j < 4; ++j)
      sl[wn * 32 + wm * 16 + lhi * 4 + j] = sums[j];
  __syncthreads();
  if (tid < 32) invsh[tid] = 1.f / (sl[tid] + sl[32 + tid]);
  __syncthreads();
  float inv4[4];
#pragma unroll
  for (int j = 0; j < 4; ++j)
    inv4[j] = invsh[wm * 16 + lhi * 4 + j];

  // ================= pass B: QK -> P(dump+LDS) -> PV; 1 barrier/tile =========
  KSTAGE(0, 0);
  asm volatile("s_waitcnt vmcnt(0)" ::: "memory");
  asm volatile("s_waitcnt lgkmcnt(0)" ::: "memory");   // inv4 reads done pre-overwrite
  __builtin_amdgcn_s_barrier();

  f32x4 ctx[2][4] = {};
  for (int t = 0; t < nkt; ++t) {
    int tn = (t + 1 < nkt) ? t + 1 : nkt - 1;
    KSTAGE(t + 1, tn);                                  // 4 vm, oldest this iter
    // V fragments direct from global (L2); consumed after barrier
    bf16x8 vb[4];
#pragma unroll
    for (int n4 = 0; n4 < 4; ++n4)
      vb[n4] = *(const bf16x8*)(V + (size_t)(w * 64 + n4 * 16 + l15) * 2048 + t * 32 + lhi * 8);

    // QK: this wave's 16 rows x 16-col strip
    const char* Kb = Ksh + (t & 1) * 16384;
    f32x4 acc = {};
    __builtin_amdgcn_s_setprio(1);
#pragma unroll
    for (int ks = 0; ks < 8; ++ks) {
      bf16x8 kb = *(const bf16x8*)(Kb + krow * 512 + ((ks * 64 + lhi * 16) ^ ksw));
      acc = mfma16(qf[ks], kb, acc);
    }
    __builtin_amdgcn_s_setprio(0);

    // exp/normalize/mask; dump f32 from regs; write bf16 to Psh[t&1]
    char* Pb = Psh + (t & 1) * 4096;
#pragma unroll
    for (int j = 0; j < 4; ++j) {
      int rr = wm * 16 + lhi * 4 + j;
      int qr = qbase + rr;
      int kc = t * 32 + krow;
      float e = (kc <= qr) ? __expf(acc[j] * 0.0625f) * inv4[j] : 0.f;
      pout[((size_t)bh * 2048 + qr) * 2048 + kc] = e;
      *(bf16_t*)(Pb + ((rr * 64 + krow * 2) ^ ((rr & 3) << 4))) = (bf16_t)e;
    }
    asm volatile("s_waitcnt lgkmcnt(0)" ::: "memory");  // P ds_writes visible
    asm volatile("s_waitcnt vmcnt(8)" ::: "memory");    // KSTAGE(t+1)+prev stores done
    __builtin_amdgcn_s_barrier();

    // PV: all 32 P rows x this wave's d-cols [w*64,+64)
    bf16x8 pa[2];
#pragma unroll
    for (int m = 0; m < 2; ++m) {
      int pr = m * 16 + l15;
      pa[m] = *(const bf16x8*)(Pb + ((pr * 64 + lhi * 16) ^ ((pr & 3) << 4)));
    }
    __builtin_amdgcn_s_setprio(1);
#pragma unroll
    for (int m = 0; m < 2; ++m)
#pragma unroll
      for (int n4 = 0; n4 < 4; ++n4)
        ctx[m][n4] = mfma16(pa[m], vb[n4], ctx[m][n4]);
    __builtin_amdgcn_s_setprio(0);
  }
#undef KSTAGE

  // ctx write: (b, s, h*256 + d) bf16
  int b = bh >> 3, h = bh & 7;
#pragma unroll
  for (int m = 0; m < 2; ++m)
#pragma unroll
    for (int n4 = 0; n4 < 4; ++n4)
#pragma unroll
      for (int j = 0; j < 4; ++j) {
        int qr = qbase + m * 16 + lhi * 4 + j;
        ctxo[((size_t)b * 2048 + qr) * 2048 + h * 256 + w * 64 + n4 * 16 + l15] = (bf16_t)ctx[m][n4][j];
      }

  // zero-fill masked region beyond causal boundary
  int zs = qbase + 32;
  for (int r = 0; r < 32; ++r) {
    size_t base2 = ((size_t)bh * 2048 + qbase + r) * 2048;
    for (int c = zs + tid * 4; c < 2048; c += 1024)
      *(float4*)(pout + base2 + c) = make_float4(0.f, 0.f, 0.f, 0.f);
  }
}

// ---------------- host launch ----------------
extern "C" void kernel_launch(void* const* d_in, const int* in_sizes, int n_in,
                              void* d_out, int out_size, void* d_ws, size_t ws_size,
                              hipStream_t stream) {
  const float* x     = (const float*)d_in[0];
  const float* ln1g  = (const float*)d_in[2];
  const float* ln1b  = (const float*)d_in[3];
  const float* wq_w  = (const float*)d_in[4];
  const float* wq_b  = (const float*)d_in[5];
  const float* wk_w  = (const float*)d_in[6];
  const float* wk_b  = (const float*)d_in[7];
  const float* wv_w  = (const float*)d_in[8];
  const float* wv_b  = (const float*)d_in[9];
  const float* dw    = (const float*)d_in[10];
  const float* db    = (const float*)d_in[11];
  const float* ln2g  = (const float*)d_in[12];
  const float* ln2b  = (const float*)d_in[13];
  const float* f1w   = (const float*)d_in[14];
  const float* f1b   = (const float*)d_in[15];
  const float* f2w   = (const float*)d_in[16];
  const float* f2b   = (const float*)d_in[17];

  char* ws = (char*)d_ws;
  const size_t MB = 1u << 20;
  float*  xn_f = (float*) (ws + 0 * MB);
  bf16_t* xn_b = (bf16_t*)(ws + 4 * MB);
  bf16_t* q_b  = (bf16_t*)(ws + 6 * MB);
  bf16_t* k_b  = (bf16_t*)(ws + 22 * MB);
  bf16_t* ctx_b= (bf16_t*)(ws + 38 * MB);
  bf16_t* vt_b = (bf16_t*)(ws + 54 * MB);
  float*  x1_f = (float*) (ws + 70 * MB);
  bf16_t* m_b  = (bf16_t*)(ws + 74 * MB);
  bf16_t* h_b  = (bf16_t*)(ws + 76 * MB);
  bf16_t* wq_bf = (bf16_t*)(ws + 84 * MB);
  bf16_t* wk_bf = wq_bf + 524288;
  bf16_t* wv_bf = wk_bf + 524288;
  bf16_t* dw_bf = wv_bf + 524288;
  bf16_t* f1_bf = dw_bf + 524288;
  bf16_t* f2_bf = f1_bf + 262144;
  float* parts_d = (float*)q_b;
  float* parts_f = (float*)k_b;

  float* out0 = (float*)d_out;
  float* pout = out0 + 1048576;

  k1_lncvt<<<3584, 256, 0, stream>>>(x, ln1g, ln1b, xn_f, xn_b,
                                     wq_w, wk_w, wv_w, dw, f1w, f2w,
                                     wq_bf, wk_bf, wv_bf, dw_bf, f1_bf, f2_bf);

  gemm_qkv<<<dim3(48, 32), 256, 0, stream>>>(xn_b, wq_bf, wk_bf, wv_bf,
                                             wq_b, wk_b, wv_b, q_b, k_b, vt_b);

  attn_fused<<<1024, 256, 0, stream>>>(q_b, k_b, vt_b, pout, ctx_b);

  gemm_part<<<dim3(2, 32, 4), 256, 0, stream>>>(ctx_b, dw_bf, 2048, 512, parts_d);
  reduce_ln<<<1024, 256, 0, stream>>>(parts_d, db, xn_f, ln2g, ln2b, x1_f, m_b);

  gemm_fc1<<<dim3(8, 32), 256, 0, stream>>>(m_b, f1_bf, f1b, h_b);

  gemm_part<<<dim3(2, 32, 4), 256, 0, stream>>>(h_b, f2_bf, 1024, 256, parts_f);
  reduce4<<<1024, 256, 0, stream>>>(parts_f, f2b, x1_f, out0);
}

// Round 10
// 266.603 us; speedup vs baseline: 1.1938x; 1.1938x over previous
//
#include <hip/hip_runtime.h>
#include <hip/hip_bf16.h>

// TransformerLayer on MI355X (gfx950). Round 10:
//  attn split restored (R5-best) with upgrades:
//   - rowsum_k: verbatim R5 (TK=64, dbuf, counted vmcnt(8))
//   - attn_pv v5: QBLK=64 x TK=64, 64 MFMA/wave/tile, ONE barrier/tile
//     (P dbuf + lgkmcnt(0)), counted vmcnt(8) only, V direct->reg,
//     P dump via LDS -> f32x4 coalesced stores (no scalar dword stores),
//     80KB LDS -> 2 blocks/CU, 512 blocks single round, paired work balance.
//  GEMM stack frozen (R5+ passing config).

typedef __bf16 bf16_t;
typedef __bf16 bf16x8 __attribute__((ext_vector_type(8)));
typedef __bf16 bf16x4 __attribute__((ext_vector_type(4)));
typedef float  f32x4  __attribute__((ext_vector_type(4)));

#define DEV __device__ __forceinline__

DEV f32x4 mfma16(bf16x8 a, bf16x8 b, f32x4 c) {
  return __builtin_amdgcn_mfma_f32_16x16x32_bf16(a, b, c, 0, 0, 0);
}

DEV void gload16(const void* g, void* l) {
  __builtin_amdgcn_global_load_lds(
      (const __attribute__((address_space(1))) unsigned int*)g,
      (__attribute__((address_space(3))) unsigned int*)l, 16, 0, 0);
}

// ---------------- fused LN1 + weight cvt (grid 1024 + 2560) ----------------
__global__ __launch_bounds__(256) void k1_lncvt(
    const float* __restrict__ x, const float* __restrict__ g, const float* __restrict__ bta,
    float* __restrict__ of, bf16_t* __restrict__ ob,
    const float* __restrict__ s0, const float* __restrict__ s1,
    const float* __restrict__ s2, const float* __restrict__ s3,
    const float* __restrict__ s4, const float* __restrict__ s5,
    bf16_t* __restrict__ d0, bf16_t* __restrict__ d1, bf16_t* __restrict__ d2,
    bf16_t* __restrict__ d3, bf16_t* __restrict__ d4, bf16_t* __restrict__ d5) {
  int bid = blockIdx.x;
  if (bid < 1024) {
    int row = bid * 4 + (threadIdx.x >> 6);
    int l = threadIdx.x & 63;
    const float4 v = *(const float4*)(x + (size_t)row * 256 + l * 4);
    float s  = v.x + v.y + v.z + v.w;
    float s2 = v.x*v.x + v.y*v.y + v.z*v.z + v.w*v.w;
#pragma unroll
    for (int o = 1; o < 64; o <<= 1) { s += __shfl_xor(s, o, 64); s2 += __shfl_xor(s2, o, 64); }
    float m   = s * (1.f/256.f);
    float var = s2 * (1.f/256.f) - m * m;
    float rs  = rsqrtf(var + 1e-9f);
    const float4 gv = *(const float4*)(g   + l * 4);
    const float4 bv = *(const float4*)(bta + l * 4);
    float4 y;
    y.x = (v.x - m) * rs * gv.x + bv.x;
    y.y = (v.y - m) * rs * gv.y + bv.y;
    y.z = (v.z - m) * rs * gv.z + bv.z;
    y.w = (v.w - m) * rs * gv.w + bv.w;
    *(float4*)(of + (size_t)row * 256 + l * 4) = y;
    bf16x4 yb = { (bf16_t)y.x, (bf16_t)y.y, (bf16_t)y.z, (bf16_t)y.w };
    *(bf16x4*)(ob + (size_t)row * 256 + l * 4) = yb;
  } else {
    int i = (bid - 1024) * 256 + threadIdx.x;
    const float* s; bf16_t* d; int off;
    if      (i < 131072) { s = s0; d = d0; off = i; }
    else if (i < 262144) { s = s1; d = d1; off = i - 131072; }
    else if (i < 393216) { s = s2; d = d2; off = i - 262144; }
    else if (i < 524288) { s = s3; d = d3; off = i - 393216; }
    else if (i < 589824) { s = s4; d = d4; off = i - 524288; }
    else                 { s = s5; d = d5; off = i - 589824; }
    float4 v = ((const float4*)s)[off];
    bf16x4 o = { (bf16_t)v.x, (bf16_t)v.y, (bf16_t)v.z, (bf16_t)v.w };
    ((bf16x4*)d)[off] = o;
  }
}

// ---------------- 2-phase double-buffered 128x128 GEMM core ----------------
DEV void gemm_core(const bf16_t* __restrict__ A, const bf16_t* __restrict__ W,
                   int lda, int row0, int col0, int k0, int kiters,
                   char* Asb, char* Bsb, f32x4 (&acc)[4][4]) {
  int tid = threadIdx.x, w = tid >> 6, l = tid & 63, l15 = l & 15, lhi = l >> 4;
  int wr = (w >> 1) * 64, wc = (w & 1) * 64;

#define STAGE(buf, kk) do {                                                   \
    char* Ad = Asb + (buf) * 8192 + w * 1024;                                 \
    char* Bd = Bsb + (buf) * 8192 + w * 1024;                                 \
    _Pragma("unroll")                                                         \
    for (int j = 0; j < 2; ++j) {                                             \
      int idx = (j * 256 + tid) * 8; int r = idx >> 5, c = idx & 31;          \
      gload16(A + (size_t)(row0 + r) * lda + (kk) + c, Ad + j * 4096);        \
      gload16(W + (size_t)(col0 + r) * lda + (kk) + c, Bd + j * 4096);        \
    } } while (0)

  STAGE(0, k0);
  for (int t = 0; t < kiters; ++t) {
    int cur = t & 1;
    if (t + 1 < kiters) {
      STAGE(cur ^ 1, k0 + (t + 1) * 32);
      asm volatile("s_waitcnt vmcnt(4)" ::: "memory");
    } else {
      asm volatile("s_waitcnt vmcnt(0)" ::: "memory");
    }
    __builtin_amdgcn_s_barrier();
    asm volatile("" ::: "memory");
    const bf16_t* As = (const bf16_t*)(Asb + cur * 8192);
    const bf16_t* Bs = (const bf16_t*)(Bsb + cur * 8192);
    bf16x8 af[4], bfr[4];
#pragma unroll
    for (int m = 0; m < 4; ++m)
      af[m] = *(const bf16x8*)(As + (wr + 16 * m + l15) * 32 + lhi * 8);
#pragma unroll
    for (int n = 0; n < 4; ++n)
      bfr[n] = *(const bf16x8*)(Bs + (wc + 16 * n + l15) * 32 + lhi * 8);
#pragma unroll
    for (int m = 0; m < 4; ++m)
#pragma unroll
      for (int n = 0; n < 4; ++n)
        acc[m][n] = mfma16(af[m], bfr[n], acc[m][n]);
    asm volatile("s_waitcnt lgkmcnt(0)" ::: "memory");
    __builtin_amdgcn_s_barrier();
  }
#undef STAGE
}

// ---------------- fused QKV: grid (48, 32); V writes V^T via LDS transpose ----------------
__global__ __launch_bounds__(256, 4) void gemm_qkv(
    const bf16_t* __restrict__ A,
    const bf16_t* __restrict__ W0, const bf16_t* __restrict__ W1, const bf16_t* __restrict__ W2,
    const float* __restrict__ b0, const float* __restrict__ b1, const float* __restrict__ b2,
    bf16_t* __restrict__ qo, bf16_t* __restrict__ ko, bf16_t* __restrict__ vto) {
  __shared__ char smem[34816];   // staging 32KB | V-transpose 128x136 bf16
  char* Asb = smem;
  char* Bsb = smem + 16384;
  int bx = blockIdx.x;
  int wsel = bx >> 4, cb = bx & 15;
  const bf16_t* W    = wsel == 0 ? W0 : (wsel == 1 ? W1 : W2);
  const float*  bias = wsel == 0 ? b0 : (wsel == 1 ? b1 : b2);
  int row0 = blockIdx.y * 128, col0 = cb * 128;
  f32x4 acc[4][4] = {};
  gemm_core(A, W, 256, row0, col0, 0, 8, Asb, Bsb, acc);

  int tid = threadIdx.x, w = tid >> 6, l = tid & 63, l15 = l & 15, lhi = l >> 4;
  int wr = (w >> 1) * 64, wc = (w & 1) * 64;

  if (wsel < 2) {
    bf16_t* out = wsel == 0 ? qo : ko;
#pragma unroll
    for (int m = 0; m < 4; ++m)
#pragma unroll
      for (int n = 0; n < 4; ++n)
#pragma unroll
        for (int j = 0; j < 4; ++j) {
          int row = row0 + wr + 16 * m + lhi * 4 + j;
          int col = col0 + wc + 16 * n + l15;
          float v = acc[m][n][j] + bias[col];
          out[((size_t)((row >> 11) * 8 + (col >> 8)) * 2048 + (row & 2047)) * 256 + (col & 255)] = (bf16_t)v;
        }
  } else {
    // V: transpose in LDS, write V^T (B,H,Dh,S)
    __syncthreads();   // full drain before overwriting staging LDS
    bf16_t* T = (bf16_t*)smem;   // [128 d][136 stride] bf16
#pragma unroll
    for (int m = 0; m < 4; ++m)
#pragma unroll
      for (int n = 0; n < 4; ++n) {
        int d = wc + 16 * n + l15;
        int s = wr + 16 * m + lhi * 4;
        bf16x4 v4;
#pragma unroll
        for (int j = 0; j < 4; ++j) v4[j] = (bf16_t)(acc[m][n][j] + bias[col0 + d]);
        *(bf16x4*)(T + d * 136 + s) = v4;
      }
    __syncthreads();
    int bh = ((row0 >> 11) << 3) + (col0 >> 8);
    int d0 = col0 & 255, s0g = row0 & 2047;
#pragma unroll
    for (int p = 0; p < 8; ++p) {
      int idx = p * 256 + tid;
      int d = idx >> 4, c = (idx & 15) * 8;
      bf16x8 v8 = *(const bf16x8*)(T + d * 136 + c);
      *(bf16x8*)(vto + ((size_t)bh * 256 + d0 + d) * 2048 + s0g + c) = v8;
    }
  }
}

// ---------------- split-K partial GEMM: N=256, grid (2, 32, 4) ----------------
__global__ __launch_bounds__(256, 4) void gemm_part(
    const bf16_t* __restrict__ A, const bf16_t* __restrict__ W,
    int lda, int ksub, float* __restrict__ parts) {
  __shared__ char Asb[2 * 8192];
  __shared__ char Bsb[2 * 8192];
  int z = blockIdx.z;
  int row0 = blockIdx.y * 128, col0 = blockIdx.x * 128;
  f32x4 acc[4][4] = {};
  gemm_core(A, W, lda, row0, col0, z * ksub, ksub >> 5, Asb, Bsb, acc);

  int tid = threadIdx.x, w = tid >> 6, l = tid & 63, l15 = l & 15, lhi = l >> 4;
  int wr = (w >> 1) * 64, wc = (w & 1) * 64;
  float* p = parts + (size_t)z * 1048576;
#pragma unroll
  for (int m = 0; m < 4; ++m)
#pragma unroll
    for (int n = 0; n < 4; ++n)
#pragma unroll
      for (int j = 0; j < 4; ++j) {
        int row = row0 + wr + 16 * m + lhi * 4 + j;
        int col = col0 + wc + 16 * n + l15;
        p[(size_t)row * 256 + col] = acc[m][n][j];
      }
}

// ---------------- reduce 4 partials + bias + residual (final out) ----------------
__global__ __launch_bounds__(256) void reduce4(
    const float* __restrict__ parts, const float* __restrict__ bias,
    const float* __restrict__ res, float* __restrict__ out) {
  int i = blockIdx.x * 256 + threadIdx.x;
  f32x4 s = *(const f32x4*)(parts + (size_t)i * 4);
  s += *(const f32x4*)(parts + 1048576 + (size_t)i * 4);
  s += *(const f32x4*)(parts + 2097152 + (size_t)i * 4);
  s += *(const f32x4*)(parts + 3145728 + (size_t)i * 4);
  s += *(const f32x4*)(res + (size_t)i * 4);
  s += *(const f32x4*)(bias + (i & 63) * 4);
  *(f32x4*)(out + (size_t)i * 4) = s;
}

// ---------------- fused dense-reduce + residual + LN2 ----------------
__global__ __launch_bounds__(256) void reduce_ln(
    const float* __restrict__ parts, const float* __restrict__ bias,
    const float* __restrict__ res, const float* __restrict__ g,
    const float* __restrict__ bta, float* __restrict__ x1o, bf16_t* __restrict__ mo) {
  int row = blockIdx.x * 4 + (threadIdx.x >> 6);
  int l = threadIdx.x & 63;
  size_t base = (size_t)row * 256 + l * 4;
  f32x4 s = *(const f32x4*)(parts + base);
  s += *(const f32x4*)(parts + 1048576 + base);
  s += *(const f32x4*)(parts + 2097152 + base);
  s += *(const f32x4*)(parts + 3145728 + base);
  s += *(const f32x4*)(res + base);
  s += *(const f32x4*)(bias + l * 4);
  *(f32x4*)(x1o + base) = s;
  float sm = s[0] + s[1] + s[2] + s[3];
  float s2 = s[0]*s[0] + s[1]*s[1] + s[2]*s[2] + s[3]*s[3];
#pragma unroll
  for (int o = 1; o < 64; o <<= 1) { sm += __shfl_xor(sm, o, 64); s2 += __shfl_xor(s2, o, 64); }
  float m   = sm * (1.f/256.f);
  float var = s2 * (1.f/256.f) - m * m;
  float rs  = rsqrtf(var + 1e-9f);
  const float4 gv = *(const float4*)(g   + l * 4);
  const float4 bv = *(const float4*)(bta + l * 4);
  bf16x4 yb;
  yb[0] = (bf16_t)((s[0] - m) * rs * gv.x + bv.x);
  yb[1] = (bf16_t)((s[1] - m) * rs * gv.y + bv.y);
  yb[2] = (bf16_t)((s[2] - m) * rs * gv.z + bv.z);
  yb[3] = (bf16_t)((s[3] - m) * rs * gv.w + bv.w);
  *(bf16x4*)(mo + base) = yb;
}

// ---------------- FC1 with gelu ----------------
__global__ __launch_bounds__(256, 4) void gemm_fc1(
    const bf16_t* __restrict__ A, const bf16_t* __restrict__ W,
    const float* __restrict__ bias, bf16_t* __restrict__ out) {
  __shared__ char Asb[2 * 8192];
  __shared__ char Bsb[2 * 8192];
  int row0 = blockIdx.y * 128, col0 = blockIdx.x * 128;
  f32x4 acc[4][4] = {};
  gemm_core(A, W, 256, row0, col0, 0, 8, Asb, Bsb, acc);

  int tid = threadIdx.x, w = tid >> 6, l = tid & 63, l15 = l & 15, lhi = l >> 4;
  int wr = (w >> 1) * 64, wc = (w & 1) * 64;
#pragma unroll
  for (int m = 0; m < 4; ++m)
#pragma unroll
    for (int n = 0; n < 4; ++n)
#pragma unroll
      for (int j = 0; j < 4; ++j) {
        int row = row0 + wr + 16 * m + lhi * 4 + j;
        int col = col0 + wc + 16 * n + l15;
        float t = acc[m][n][j] + bias[col];
        float ge = 0.5f * t * (1.f + tanhf(0.7978845608f * t * (1.f + 0.044715f * t * t)));
        out[(size_t)row * 1024 + col] = (bf16_t)ge;
      }
}

// ---------------- rowsum kernel (R5-proven): sums -> rsg = 1/rowsum ----------------
__global__ __launch_bounds__(256, 2) void rowsum_k(
    const bf16_t* __restrict__ qg, const bf16_t* __restrict__ kg,
    float* __restrict__ rsg) {
  __shared__ bf16_t Ksh[2][64 * 256];
  __shared__ float  sl[2][64];
  int bx = blockIdx.x;
  int bh = bx & 15, qt = 31 - (bx >> 4);
  int tid = threadIdx.x, w = tid >> 6, l = tid & 63;
  int l15 = l & 15, lhi = l >> 4;
  int wm = w >> 1, wn = w & 1;
  const bf16_t* Q   = qg + (size_t)bh * 2048 * 256;
  const bf16_t* Kg2 = kg + (size_t)bh * 2048 * 256;
  int qbase = qt * 64;
  int nkt = qt + 1;

  bf16x8 qf[2][8];
#pragma unroll
  for (int m = 0; m < 2; ++m)
#pragma unroll
    for (int ks = 0; ks < 8; ++ks)
      qf[m][ks] = *(const bf16x8*)(Q + (size_t)(qbase + wm * 32 + m * 16 + l15) * 256 + ks * 32 + lhi * 8);

#define RSTAGE(t_) do {                                                        \
    char* dst = (char*)Ksh[(t_) & 1] + w * 1024;                               \
    _Pragma("unroll")                                                          \
    for (int j = 0; j < 8; ++j) {                                              \
      int idx = (j * 256 + tid) * 16; int r = idx >> 9;                        \
      int co = (idx & 511) ^ ((r & 7) << 4);                                   \
      gload16(Kg2 + (size_t)((t_) * 64 + r) * 256 + (co >> 1), dst + j * 4096);\
    } } while (0)

  RSTAGE(0);
  if (nkt > 1) RSTAGE(1);

  float sums[2][4] = {};
  for (int t = 0; t < nkt; ++t) {
    if (t + 1 < nkt) asm volatile("s_waitcnt vmcnt(8)" ::: "memory");
    else             asm volatile("s_waitcnt vmcnt(0)" ::: "memory");
    __builtin_amdgcn_s_barrier();
    const char* Kb = (const char*)Ksh[t & 1];
    f32x4 acc[2][2] = {};
    __builtin_amdgcn_s_setprio(1);
#pragma unroll
    for (int ks = 0; ks < 8; ++ks) {
#pragma unroll
      for (int n2 = 0; n2 < 2; ++n2) {
        int row = wn * 32 + n2 * 16 + l15;
        bf16x8 kb = *(const bf16x8*)(Kb + row * 512 + ((ks * 64 + lhi * 16) ^ ((row & 7) << 4)));
#pragma unroll
        for (int m = 0; m < 2; ++m)
          acc[m][n2] = mfma16(qf[m][ks], kb, acc[m][n2]);
      }
    }
    __builtin_amdgcn_s_setprio(0);
#pragma unroll
    for (int m = 0; m < 2; ++m)
#pragma unroll
      for (int n2 = 0; n2 < 2; ++n2)
#pragma unroll
        for (int j = 0; j < 4; ++j) {
          int qr = qbase + wm * 32 + m * 16 + lhi * 4 + j;
          int kc = t * 64 + wn * 32 + n2 * 16 + l15;
          sums[m][j] += (kc <= qr) ? __expf(acc[m][n2][j] * 0.0625f) : 0.f;
        }
    asm volatile("s_waitcnt lgkmcnt(0)" ::: "memory");
    __builtin_amdgcn_s_barrier();
    if (t + 2 < nkt) RSTAGE(t + 2);
  }
#undef RSTAGE

#pragma unroll
  for (int m = 0; m < 2; ++m)
#pragma unroll
    for (int j = 0; j < 4; ++j) {
#pragma unroll
      for (int o = 1; o < 16; o <<= 1) sums[m][j] += __shfl_xor(sums[m][j], o, 64);
    }
  if (l15 == 0) {
#pragma unroll
    for (int m = 0; m < 2; ++m)
#pragma unroll
      for (int j = 0; j < 4; ++j)
        sl[wn][wm * 32 + m * 16 + lhi * 4 + j] = sums[m][j];
  }
  __syncthreads();
  if (tid < 64)
    rsg[(size_t)bh * 2048 + qbase + tid] = 1.f / (sl[0][tid] + sl[1][tid]);
}

// ---------------- attn_pv v5: QBLK=64, TK=64, one barrier/tile ----------------
// grid 512: bh = bx&15; b<256: qt=31-(b>>4) (big first); b>=256: qt=(b-256)>>4.
__global__ __launch_bounds__(256, 2) void attn_pv(
    const bf16_t* __restrict__ qg, const bf16_t* __restrict__ kg,
    const bf16_t* __restrict__ vt, const float* __restrict__ rsg,
    float* __restrict__ pout, bf16_t* __restrict__ ctxo) {
  __shared__ __align__(16) char smem[81920];
  char* Ksh = smem;               // 2 x 32KB K dbuf (64 x 256 bf16)
  char* Psh = smem + 65536;       // 2 x 8KB P dbuf (64 x 64 bf16)
  int bx = blockIdx.x;
  int bh = bx & 15;
  int qt = (bx < 256) ? (31 - (bx >> 4)) : ((bx - 256) >> 4);
  int qbase = qt * 64;
  int nkt = qt + 1;               // TK=64 tiles

  int tid = threadIdx.x, w = tid >> 6, l = tid & 63;
  int l15 = l & 15, lhi = l >> 4;
  int wm = w >> 1, wn = w & 1;
  const bf16_t* Q = qg + (size_t)bh * 2048 * 256;
  const bf16_t* K = kg + (size_t)bh * 2048 * 256;
  const bf16_t* V = vt + (size_t)bh * 256 * 2048;

  // Q fragments: rows qbase + wm*32 + m*16 + l15
  bf16x8 qf[2][8];
#pragma unroll
  for (int m = 0; m < 2; ++m)
#pragma unroll
    for (int ks = 0; ks < 8; ++ks)
      qf[m][ks] = *(const bf16x8*)(Q + (size_t)(qbase + wm * 32 + m * 16 + l15) * 256 + ks * 32 + lhi * 8);

  // inverse rowsums for this lane's 8 rows
  float inv4[2][4];
#pragma unroll
  for (int m = 0; m < 2; ++m)
#pragma unroll
    for (int j = 0; j < 4; ++j)
      inv4[m][j] = rsg[(size_t)bh * 2048 + qbase + wm * 32 + m * 16 + lhi * 4 + j];

  // K stage TK=64: LDS linear dest; source pre-swizzled by ^((r&15)<<4)
#define KSTAGE(td_, ts_) do {                                                  \
    char* dst0 = Ksh + ((td_) & 1) * 32768 + w * 8192;                         \
    _Pragma("unroll")                                                          \
    for (int j5 = 0; j5 < 8; ++j5) {                                           \
      int idxb = w * 8192 + j5 * 1024 + (tid & 63) * 16;                       \
      int r5 = idxb >> 9; int inner = idxb & 511;                              \
      int colb = inner ^ ((r5 & 15) << 4);                                     \
      gload16(K + (size_t)((ts_) * 64 + r5) * 256 + (colb >> 1), dst0 + j5 * 1024); \
    } } while (0)

  KSTAGE(0, 0);
  asm volatile("s_waitcnt vmcnt(0)" ::: "memory");
  __builtin_amdgcn_s_barrier();

  f32x4 ctx[4][4] = {};
  for (int t = 0; t < nkt; ++t) {
    int tn = (t + 1 < nkt) ? t + 1 : nkt - 1;
    KSTAGE(t + 1, tn);                                  // 8 vm
    // V fragments direct from global (L2); consumed after barrier
    bf16x8 vb[4][2];
#pragma unroll
    for (int n4 = 0; n4 < 4; ++n4)
#pragma unroll
      for (int ks2 = 0; ks2 < 2; ++ks2)
        vb[n4][ks2] = *(const bf16x8*)(V + (size_t)(w * 64 + n4 * 16 + l15) * 2048 + t * 64 + ks2 * 32 + lhi * 8);

    // QK: wave (wm,wn): rows [wm*32,+32) x cols [wn*32,+32)
    const char* Kb = Ksh + (t & 1) * 32768;
    f32x4 acc[2][2] = {};
    __builtin_amdgcn_s_setprio(1);
#pragma unroll
    for (int ks = 0; ks < 8; ++ks) {
#pragma unroll
      for (int n2 = 0; n2 < 2; ++n2) {
        int krow = wn * 32 + n2 * 16 + l15;
        bf16x8 kb = *(const bf16x8*)(Kb + krow * 512 + ((ks * 64 + lhi * 16) ^ ((krow & 15) << 4)));
#pragma unroll
        for (int m = 0; m < 2; ++m)
          acc[m][n2] = mfma16(qf[m][ks], kb, acc[m][n2]);
      }
    }
    __builtin_amdgcn_s_setprio(0);

    // exp/normalize/mask -> Psh[t&1] (bf16, swz (rr&7)<<4)
    char* Pb = Psh + (t & 1) * 8192;
#pragma unroll
    for (int m = 0; m < 2; ++m)
#pragma unroll
      for (int n2 = 0; n2 < 2; ++n2)
#pragma unroll
        for (int j = 0; j < 4; ++j) {
          int rr = wm * 32 + m * 16 + lhi * 4 + j;
          int cc = wn * 32 + n2 * 16 + l15;
          int qr = qbase + rr;
          int kc = t * 64 + cc;
          float e = (kc <= qr) ? __expf(acc[m][n2][j] * 0.0625f) * inv4[m][j] : 0.f;
          *(bf16_t*)(Pb + rr * 128 + ((cc * 2) ^ ((rr & 7) << 4))) = (bf16_t)e;
        }
    asm volatile("s_waitcnt lgkmcnt(0)" ::: "memory");  // P writes visible
    asm volatile("s_waitcnt vmcnt(8)" ::: "memory");    // KSTAGE(t+1) done; vb in flight
    __builtin_amdgcn_s_barrier();

    // dump Psh -> pout (f32x4 coalesced): thread -> row tid>>2, 16 cols
    {
      int prow = tid >> 2, c0 = (tid & 3) * 16;
      float* dst = pout + ((size_t)bh * 2048 + qbase + prow) * 2048 + t * 64 + c0;
#pragma unroll
      for (int h8 = 0; h8 < 2; ++h8) {
        bf16x8 p8 = *(const bf16x8*)(Pb + prow * 128 + (((c0 + h8 * 8) * 2) ^ ((prow & 7) << 4)));
        f32x4 lo = { (float)p8[0], (float)p8[1], (float)p8[2], (float)p8[3] };
        f32x4 hi = { (float)p8[4], (float)p8[5], (float)p8[6], (float)p8[7] };
        *(f32x4*)(dst + h8 * 8) = lo;
        *(f32x4*)(dst + h8 * 8 + 4) = hi;
      }
    }

    // PV: all 64 P rows x this wave's d-cols [w*64,+64)
    __builtin_amdgcn_s_setprio(1);
#pragma unroll
    for (int ks2 = 0; ks2 < 2; ++ks2) {
      bf16x8 pa[4];
#pragma unroll
      for (int m4 = 0; m4 < 4; ++m4) {
        int pr = m4 * 16 + l15;
        pa[m4] = *(const bf16x8*)(Pb + pr * 128 + (((ks2 * 64 + lhi * 16)) ^ ((pr & 7) << 4)));
      }
#pragma unroll
      for (int m4 = 0; m4 < 4; ++m4)
#pragma unroll
        for (int n4 = 0; n4 < 4; ++n4)
          ctx[m4][n4] = mfma16(pa[m4], vb[n4][ks2], ctx[m4][n4]);
    }
    __builtin_amdgcn_s_setprio(0);
  }
#undef KSTAGE

  // ctx write: (b, s, h*256 + d) bf16
  int b = bh >> 3, h = bh & 7;
#pragma unroll
  for (int m4 = 0; m4 < 4; ++m4)
#pragma unroll
    for (int n4 = 0; n4 < 4; ++n4)
#pragma unroll
      for (int j = 0; j < 4; ++j) {
        int qr = qbase + m4 * 16 + lhi * 4 + j;
        ctxo[((size_t)b * 2048 + qr) * 2048 + h * 256 + w * 64 + n4 * 16 + l15] = (bf16_t)ctx[m4][n4][j];
      }

  // zero-fill masked region beyond causal boundary
  int zs = qbase + 64;
  for (int r = 0; r < 64; ++r) {
    size_t base2 = ((size_t)bh * 2048 + qbase + r) * 2048;
    for (int c = zs + tid * 4; c < 2048; c += 1024)
      *(float4*)(pout + base2 + c) = make_float4(0.f, 0.f, 0.f, 0.f);
  }
}

// ---------------- host launch ----------------
extern "C" void kernel_launch(void* const* d_in, const int* in_sizes, int n_in,
                              void* d_out, int out_size, void* d_ws, size_t ws_size,
                              hipStream_t stream) {
  const float* x     = (const float*)d_in[0];
  const float* ln1g  = (const float*)d_in[2];
  const float* ln1b  = (const float*)d_in[3];
  const float* wq_w  = (const float*)d_in[4];
  const float* wq_b  = (const float*)d_in[5];
  const float* wk_w  = (const float*)d_in[6];
  const float* wk_b  = (const float*)d_in[7];
  const float* wv_w  = (const float*)d_in[8];
  const float* wv_b  = (const float*)d_in[9];
  const float* dw    = (const float*)d_in[10];
  const float* db    = (const float*)d_in[11];
  const float* ln2g  = (const float*)d_in[12];
  const float* ln2b  = (const float*)d_in[13];
  const float* f1w   = (const float*)d_in[14];
  const float* f1b   = (const float*)d_in[15];
  const float* f2w   = (const float*)d_in[16];
  const float* f2b   = (const float*)d_in[17];

  char* ws = (char*)d_ws;
  const size_t MB = 1u << 20;
  float*  xn_f = (float*) (ws + 0 * MB);
  bf16_t* xn_b = (bf16_t*)(ws + 4 * MB);
  bf16_t* q_b  = (bf16_t*)(ws + 6 * MB);
  bf16_t* k_b  = (bf16_t*)(ws + 22 * MB);
  bf16_t* ctx_b= (bf16_t*)(ws + 38 * MB);
  bf16_t* vt_b = (bf16_t*)(ws + 54 * MB);
  float*  x1_f = (float*) (ws + 70 * MB);
  bf16_t* m_b  = (bf16_t*)(ws + 74 * MB);
  bf16_t* h_b  = (bf16_t*)(ws + 76 * MB);
  bf16_t* wq_bf = (bf16_t*)(ws + 84 * MB);
  bf16_t* wk_bf = wq_bf + 524288;
  bf16_t* wv_bf = wk_bf + 524288;
  bf16_t* dw_bf = wv_bf + 524288;
  bf16_t* f1_bf = dw_bf + 524288;
  bf16_t* f2_bf = f1_bf + 262144;
  float*  rs_f  = (float*)(ws + 90 * MB);
  float* parts_d = (float*)q_b;
  float* parts_f = (float*)k_b;

  float* out0 = (float*)d_out;
  float* pout = out0 + 1048576;

  k1_lncvt<<<3584, 256, 0, stream>>>(x, ln1g, ln1b, xn_f, xn_b,
                                     wq_w, wk_w, wv_w, dw, f1w, f2w,
                                     wq_bf, wk_bf, wv_bf, dw_bf, f1_bf, f2_bf);

  gemm_qkv<<<dim3(48, 32), 256, 0, stream>>>(xn_b, wq_bf, wk_bf, wv_bf,
                                             wq_b, wk_b, wv_b, q_b, k_b, vt_b);

  rowsum_k<<<512, 256, 0, stream>>>(q_b, k_b, rs_f);

  attn_pv<<<512, 256, 0, stream>>>(q_b, k_b, vt_b, rs_f, pout, ctx_b);

  gemm_part<<<dim3(2, 32, 4), 256, 0, stream>>>(ctx_b, dw_bf, 2048, 512, parts_d);
  reduce_ln<<<1024, 256, 0, stream>>>(parts_d, db, xn_f, ln2g, ln2b, x1_f, m_b);

  gemm_fc1<<<dim3(8, 32), 256, 0, stream>>>(m_b, f1_bf, f1b, h_b);

  gemm_part<<<dim3(2, 32, 4), 256, 0, stream>>>(h_b, f2_bf, 1024, 256, parts_f);
  reduce4<<<1024, 256, 0, stream>>>(parts_f, f2b, x1_f, out0);
}

// Round 11
// 225.196 us; speedup vs baseline: 1.4134x; 1.1839x over previous
//
#include <hip/hip_runtime.h>
#include <hip/hip_bf16.h>

// TransformerLayer on MI355X (gfx950). Round 11:
//  attn_pv v6 = R5's proven staged TK=32 structure (115us) + 3 cuts:
//   - V re-staged via global_load_lds (R10's direct V was an 8x L2 amplifier)
//   - P double-buffer -> 2 barriers/tile (was 3)
//   - P dump to pout directly from registers (f32, no LDS round trip),
//     stores counted in vmcnt(8), never drained in-loop
//  rowsum_k + GEMM stack byte-identical to R10 (proven).

typedef __bf16 bf16_t;
typedef __bf16 bf16x8 __attribute__((ext_vector_type(8)));
typedef __bf16 bf16x4 __attribute__((ext_vector_type(4)));
typedef float  f32x4  __attribute__((ext_vector_type(4)));

#define DEV __device__ __forceinline__

DEV f32x4 mfma16(bf16x8 a, bf16x8 b, f32x4 c) {
  return __builtin_amdgcn_mfma_f32_16x16x32_bf16(a, b, c, 0, 0, 0);
}

DEV void gload16(const void* g, void* l) {
  __builtin_amdgcn_global_load_lds(
      (const __attribute__((address_space(1))) unsigned int*)g,
      (__attribute__((address_space(3))) unsigned int*)l, 16, 0, 0);
}

// ---------------- fused LN1 + weight cvt (grid 1024 + 2560) ----------------
__global__ __launch_bounds__(256) void k1_lncvt(
    const float* __restrict__ x, const float* __restrict__ g, const float* __restrict__ bta,
    float* __restrict__ of, bf16_t* __restrict__ ob,
    const float* __restrict__ s0, const float* __restrict__ s1,
    const float* __restrict__ s2, const float* __restrict__ s3,
    const float* __restrict__ s4, const float* __restrict__ s5,
    bf16_t* __restrict__ d0, bf16_t* __restrict__ d1, bf16_t* __restrict__ d2,
    bf16_t* __restrict__ d3, bf16_t* __restrict__ d4, bf16_t* __restrict__ d5) {
  int bid = blockIdx.x;
  if (bid < 1024) {
    int row = bid * 4 + (threadIdx.x >> 6);
    int l = threadIdx.x & 63;
    const float4 v = *(const float4*)(x + (size_t)row * 256 + l * 4);
    float s  = v.x + v.y + v.z + v.w;
    float s2 = v.x*v.x + v.y*v.y + v.z*v.z + v.w*v.w;
#pragma unroll
    for (int o = 1; o < 64; o <<= 1) { s += __shfl_xor(s, o, 64); s2 += __shfl_xor(s2, o, 64); }
    float m   = s * (1.f/256.f);
    float var = s2 * (1.f/256.f) - m * m;
    float rs  = rsqrtf(var + 1e-9f);
    const float4 gv = *(const float4*)(g   + l * 4);
    const float4 bv = *(const float4*)(bta + l * 4);
    float4 y;
    y.x = (v.x - m) * rs * gv.x + bv.x;
    y.y = (v.y - m) * rs * gv.y + bv.y;
    y.z = (v.z - m) * rs * gv.z + bv.z;
    y.w = (v.w - m) * rs * gv.w + bv.w;
    *(float4*)(of + (size_t)row * 256 + l * 4) = y;
    bf16x4 yb = { (bf16_t)y.x, (bf16_t)y.y, (bf16_t)y.z, (bf16_t)y.w };
    *(bf16x4*)(ob + (size_t)row * 256 + l * 4) = yb;
  } else {
    int i = (bid - 1024) * 256 + threadIdx.x;
    const float* s; bf16_t* d; int off;
    if      (i < 131072) { s = s0; d = d0; off = i; }
    else if (i < 262144) { s = s1; d = d1; off = i - 131072; }
    else if (i < 393216) { s = s2; d = d2; off = i - 262144; }
    else if (i < 524288) { s = s3; d = d3; off = i - 393216; }
    else if (i < 589824) { s = s4; d = d4; off = i - 524288; }
    else                 { s = s5; d = d5; off = i - 589824; }
    float4 v = ((const float4*)s)[off];
    bf16x4 o = { (bf16_t)v.x, (bf16_t)v.y, (bf16_t)v.z, (bf16_t)v.w };
    ((bf16x4*)d)[off] = o;
  }
}

// ---------------- 2-phase double-buffered 128x128 GEMM core ----------------
DEV void gemm_core(const bf16_t* __restrict__ A, const bf16_t* __restrict__ W,
                   int lda, int row0, int col0, int k0, int kiters,
                   char* Asb, char* Bsb, f32x4 (&acc)[4][4]) {
  int tid = threadIdx.x, w = tid >> 6, l = tid & 63, l15 = l & 15, lhi = l >> 4;
  int wr = (w >> 1) * 64, wc = (w & 1) * 64;

#define STAGE(buf, kk) do {                                                   \
    char* Ad = Asb + (buf) * 8192 + w * 1024;                                 \
    char* Bd = Bsb + (buf) * 8192 + w * 1024;                                 \
    _Pragma("unroll")                                                         \
    for (int j = 0; j < 2; ++j) {                                             \
      int idx = (j * 256 + tid) * 8; int r = idx >> 5, c = idx & 31;          \
      gload16(A + (size_t)(row0 + r) * lda + (kk) + c, Ad + j * 4096);        \
      gload16(W + (size_t)(col0 + r) * lda + (kk) + c, Bd + j * 4096);        \
    } } while (0)

  STAGE(0, k0);
  for (int t = 0; t < kiters; ++t) {
    int cur = t & 1;
    if (t + 1 < kiters) {
      STAGE(cur ^ 1, k0 + (t + 1) * 32);
      asm volatile("s_waitcnt vmcnt(4)" ::: "memory");
    } else {
      asm volatile("s_waitcnt vmcnt(0)" ::: "memory");
    }
    __builtin_amdgcn_s_barrier();
    asm volatile("" ::: "memory");
    const bf16_t* As = (const bf16_t*)(Asb + cur * 8192);
    const bf16_t* Bs = (const bf16_t*)(Bsb + cur * 8192);
    bf16x8 af[4], bfr[4];
#pragma unroll
    for (int m = 0; m < 4; ++m)
      af[m] = *(const bf16x8*)(As + (wr + 16 * m + l15) * 32 + lhi * 8);
#pragma unroll
    for (int n = 0; n < 4; ++n)
      bfr[n] = *(const bf16x8*)(Bs + (wc + 16 * n + l15) * 32 + lhi * 8);
#pragma unroll
    for (int m = 0; m < 4; ++m)
#pragma unroll
      for (int n = 0; n < 4; ++n)
        acc[m][n] = mfma16(af[m], bfr[n], acc[m][n]);
    asm volatile("s_waitcnt lgkmcnt(0)" ::: "memory");
    __builtin_amdgcn_s_barrier();
  }
#undef STAGE
}

// ---------------- fused QKV: grid (48, 32); V writes V^T via LDS transpose ----------------
__global__ __launch_bounds__(256, 4) void gemm_qkv(
    const bf16_t* __restrict__ A,
    const bf16_t* __restrict__ W0, const bf16_t* __restrict__ W1, const bf16_t* __restrict__ W2,
    const float* __restrict__ b0, const float* __restrict__ b1, const float* __restrict__ b2,
    bf16_t* __restrict__ qo, bf16_t* __restrict__ ko, bf16_t* __restrict__ vto) {
  __shared__ char smem[34816];   // staging 32KB | V-transpose 128x136 bf16
  char* Asb = smem;
  char* Bsb = smem + 16384;
  int bx = blockIdx.x;
  int wsel = bx >> 4, cb = bx & 15;
  const bf16_t* W    = wsel == 0 ? W0 : (wsel == 1 ? W1 : W2);
  const float*  bias = wsel == 0 ? b0 : (wsel == 1 ? b1 : b2);
  int row0 = blockIdx.y * 128, col0 = cb * 128;
  f32x4 acc[4][4] = {};
  gemm_core(A, W, 256, row0, col0, 0, 8, Asb, Bsb, acc);

  int tid = threadIdx.x, w = tid >> 6, l = tid & 63, l15 = l & 15, lhi = l >> 4;
  int wr = (w >> 1) * 64, wc = (w & 1) * 64;

  if (wsel < 2) {
    bf16_t* out = wsel == 0 ? qo : ko;
#pragma unroll
    for (int m = 0; m < 4; ++m)
#pragma unroll
      for (int n = 0; n < 4; ++n)
#pragma unroll
        for (int j = 0; j < 4; ++j) {
          int row = row0 + wr + 16 * m + lhi * 4 + j;
          int col = col0 + wc + 16 * n + l15;
          float v = acc[m][n][j] + bias[col];
          out[((size_t)((row >> 11) * 8 + (col >> 8)) * 2048 + (row & 2047)) * 256 + (col & 255)] = (bf16_t)v;
        }
  } else {
    // V: transpose in LDS, write V^T (B,H,Dh,S)
    __syncthreads();   // full drain before overwriting staging LDS
    bf16_t* T = (bf16_t*)smem;   // [128 d][136 stride] bf16
#pragma unroll
    for (int m = 0; m < 4; ++m)
#pragma unroll
      for (int n = 0; n < 4; ++n) {
        int d = wc + 16 * n + l15;
        int s = wr + 16 * m + lhi * 4;
        bf16x4 v4;
#pragma unroll
        for (int j = 0; j < 4; ++j) v4[j] = (bf16_t)(acc[m][n][j] + bias[col0 + d]);
        *(bf16x4*)(T + d * 136 + s) = v4;
      }
    __syncthreads();
    int bh = ((row0 >> 11) << 3) + (col0 >> 8);
    int d0 = col0 & 255, s0g = row0 & 2047;
#pragma unroll
    for (int p = 0; p < 8; ++p) {
      int idx = p * 256 + tid;
      int d = idx >> 4, c = (idx & 15) * 8;
      bf16x8 v8 = *(const bf16x8*)(T + d * 136 + c);
      *(bf16x8*)(vto + ((size_t)bh * 256 + d0 + d) * 2048 + s0g + c) = v8;
    }
  }
}

// ---------------- split-K partial GEMM: N=256, grid (2, 32, 4) ----------------
__global__ __launch_bounds__(256, 4) void gemm_part(
    const bf16_t* __restrict__ A, const bf16_t* __restrict__ W,
    int lda, int ksub, float* __restrict__ parts) {
  __shared__ char Asb[2 * 8192];
  __shared__ char Bsb[2 * 8192];
  int z = blockIdx.z;
  int row0 = blockIdx.y * 128, col0 = blockIdx.x * 128;
  f32x4 acc[4][4] = {};
  gemm_core(A, W, lda, row0, col0, z * ksub, ksub >> 5, Asb, Bsb, acc);

  int tid = threadIdx.x, w = tid >> 6, l = tid & 63, l15 = l & 15, lhi = l >> 4;
  int wr = (w >> 1) * 64, wc = (w & 1) * 64;
  float* p = parts + (size_t)z * 1048576;
#pragma unroll
  for (int m = 0; m < 4; ++m)
#pragma unroll
    for (int n = 0; n < 4; ++n)
#pragma unroll
      for (int j = 0; j < 4; ++j) {
        int row = row0 + wr + 16 * m + lhi * 4 + j;
        int col = col0 + wc + 16 * n + l15;
        p[(size_t)row * 256 + col] = acc[m][n][j];
      }
}

// ---------------- reduce 4 partials + bias + residual (final out) ----------------
__global__ __launch_bounds__(256) void reduce4(
    const float* __restrict__ parts, const float* __restrict__ bias,
    const float* __restrict__ res, float* __restrict__ out) {
  int i = blockIdx.x * 256 + threadIdx.x;
  f32x4 s = *(const f32x4*)(parts + (size_t)i * 4);
  s += *(const f32x4*)(parts + 1048576 + (size_t)i * 4);
  s += *(const f32x4*)(parts + 2097152 + (size_t)i * 4);
  s += *(const f32x4*)(parts + 3145728 + (size_t)i * 4);
  s += *(const f32x4*)(res + (size_t)i * 4);
  s += *(const f32x4*)(bias + (i & 63) * 4);
  *(f32x4*)(out + (size_t)i * 4) = s;
}

// ---------------- fused dense-reduce + residual + LN2 ----------------
__global__ __launch_bounds__(256) void reduce_ln(
    const float* __restrict__ parts, const float* __restrict__ bias,
    const float* __restrict__ res, const float* __restrict__ g,
    const float* __restrict__ bta, float* __restrict__ x1o, bf16_t* __restrict__ mo) {
  int row = blockIdx.x * 4 + (threadIdx.x >> 6);
  int l = threadIdx.x & 63;
  size_t base = (size_t)row * 256 + l * 4;
  f32x4 s = *(const f32x4*)(parts + base);
  s += *(const f32x4*)(parts + 1048576 + base);
  s += *(const f32x4*)(parts + 2097152 + base);
  s += *(const f32x4*)(parts + 3145728 + base);
  s += *(const f32x4*)(res + base);
  s += *(const f32x4*)(bias + l * 4);
  *(f32x4*)(x1o + base) = s;
  float sm = s[0] + s[1] + s[2] + s[3];
  float s2 = s[0]*s[0] + s[1]*s[1] + s[2]*s[2] + s[3]*s[3];
#pragma unroll
  for (int o = 1; o < 64; o <<= 1) { sm += __shfl_xor(sm, o, 64); s2 += __shfl_xor(s2, o, 64); }
  float m   = sm * (1.f/256.f);
  float var = s2 * (1.f/256.f) - m * m;
  float rs  = rsqrtf(var + 1e-9f);
  const float4 gv = *(const float4*)(g   + l * 4);
  const float4 bv = *(const float4*)(bta + l * 4);
  bf16x4 yb;
  yb[0] = (bf16_t)((s[0] - m) * rs * gv.x + bv.x);
  yb[1] = (bf16_t)((s[1] - m) * rs * gv.y + bv.y);
  yb[2] = (bf16_t)((s[2] - m) * rs * gv.z + bv.z);
  yb[3] = (bf16_t)((s[3] - m) * rs * gv.w + bv.w);
  *(bf16x4*)(mo + base) = yb;
}

// ---------------- FC1 with gelu ----------------
__global__ __launch_bounds__(256, 4) void gemm_fc1(
    const bf16_t* __restrict__ A, const bf16_t* __restrict__ W,
    const float* __restrict__ bias, bf16_t* __restrict__ out) {
  __shared__ char Asb[2 * 8192];
  __shared__ char Bsb[2 * 8192];
  int row0 = blockIdx.y * 128, col0 = blockIdx.x * 128;
  f32x4 acc[4][4] = {};
  gemm_core(A, W, 256, row0, col0, 0, 8, Asb, Bsb, acc);

  int tid = threadIdx.x, w = tid >> 6, l = tid & 63, l15 = l & 15, lhi = l >> 4;
  int wr = (w >> 1) * 64, wc = (w & 1) * 64;
#pragma unroll
  for (int m = 0; m < 4; ++m)
#pragma unroll
    for (int n = 0; n < 4; ++n)
#pragma unroll
      for (int j = 0; j < 4; ++j) {
        int row = row0 + wr + 16 * m + lhi * 4 + j;
        int col = col0 + wc + 16 * n + l15;
        float t = acc[m][n][j] + bias[col];
        float ge = 0.5f * t * (1.f + tanhf(0.7978845608f * t * (1.f + 0.044715f * t * t)));
        out[(size_t)row * 1024 + col] = (bf16_t)ge;
      }
}

// ---------------- rowsum kernel (R5-proven): sums -> rsg = 1/rowsum ----------------
__global__ __launch_bounds__(256, 2) void rowsum_k(
    const bf16_t* __restrict__ qg, const bf16_t* __restrict__ kg,
    float* __restrict__ rsg) {
  __shared__ bf16_t Ksh[2][64 * 256];
  __shared__ float  sl[2][64];
  int bx = blockIdx.x;
  int bh = bx & 15, qt = 31 - (bx >> 4);
  int tid = threadIdx.x, w = tid >> 6, l = tid & 63;
  int l15 = l & 15, lhi = l >> 4;
  int wm = w >> 1, wn = w & 1;
  const bf16_t* Q   = qg + (size_t)bh * 2048 * 256;
  const bf16_t* Kg2 = kg + (size_t)bh * 2048 * 256;
  int qbase = qt * 64;
  int nkt = qt + 1;

  bf16x8 qf[2][8];
#pragma unroll
  for (int m = 0; m < 2; ++m)
#pragma unroll
    for (int ks = 0; ks < 8; ++ks)
      qf[m][ks] = *(const bf16x8*)(Q + (size_t)(qbase + wm * 32 + m * 16 + l15) * 256 + ks * 32 + lhi * 8);

#define RSTAGE(t_) do {                                                        \
    char* dst = (char*)Ksh[(t_) & 1] + w * 1024;                               \
    _Pragma("unroll")                                                          \
    for (int j = 0; j < 8; ++j) {                                              \
      int idx = (j * 256 + tid) * 16; int r = idx >> 9;                        \
      int co = (idx & 511) ^ ((r & 7) << 4);                                   \
      gload16(Kg2 + (size_t)((t_) * 64 + r) * 256 + (co >> 1), dst + j * 4096);\
    } } while (0)

  RSTAGE(0);
  if (nkt > 1) RSTAGE(1);

  float sums[2][4] = {};
  for (int t = 0; t < nkt; ++t) {
    if (t + 1 < nkt) asm volatile("s_waitcnt vmcnt(8)" ::: "memory");
    else             asm volatile("s_waitcnt vmcnt(0)" ::: "memory");
    __builtin_amdgcn_s_barrier();
    const char* Kb = (const char*)Ksh[t & 1];
    f32x4 acc[2][2] = {};
    __builtin_amdgcn_s_setprio(1);
#pragma unroll
    for (int ks = 0; ks < 8; ++ks) {
#pragma unroll
      for (int n2 = 0; n2 < 2; ++n2) {
        int row = wn * 32 + n2 * 16 + l15;
        bf16x8 kb = *(const bf16x8*)(Kb + row * 512 + ((ks * 64 + lhi * 16) ^ ((row & 7) << 4)));
#pragma unroll
        for (int m = 0; m < 2; ++m)
          acc[m][n2] = mfma16(qf[m][ks], kb, acc[m][n2]);
      }
    }
    __builtin_amdgcn_s_setprio(0);
#pragma unroll
    for (int m = 0; m < 2; ++m)
#pragma unroll
      for (int n2 = 0; n2 < 2; ++n2)
#pragma unroll
        for (int j = 0; j < 4; ++j) {
          int qr = qbase + wm * 32 + m * 16 + lhi * 4 + j;
          int kc = t * 64 + wn * 32 + n2 * 16 + l15;
          sums[m][j] += (kc <= qr) ? __expf(acc[m][n2][j] * 0.0625f) : 0.f;
        }
    asm volatile("s_waitcnt lgkmcnt(0)" ::: "memory");
    __builtin_amdgcn_s_barrier();
    if (t + 2 < nkt) RSTAGE(t + 2);
  }
#undef RSTAGE

#pragma unroll
  for (int m = 0; m < 2; ++m)
#pragma unroll
    for (int j = 0; j < 4; ++j) {
#pragma unroll
      for (int o = 1; o < 16; o <<= 1) sums[m][j] += __shfl_xor(sums[m][j], o, 64);
    }
  if (l15 == 0) {
#pragma unroll
    for (int m = 0; m < 2; ++m)
#pragma unroll
      for (int j = 0; j < 4; ++j)
        sl[wn][wm * 32 + m * 16 + lhi * 4 + j] = sums[m][j];
  }
  __syncthreads();
  if (tid < 64)
    rsg[(size_t)bh * 2048 + qbase + tid] = 1.f / (sl[0][tid] + sl[1][tid]);
}

// ---------------- attn_pv v6: QBLK=64, TK=32, staged K+V, 2 barriers/tile ----
// grid 512: bh = bx&15; b<256: qt=31-(b>>4) (big first); b>=256: qt=(b-256)>>4.
__global__ __launch_bounds__(256, 2) void attn_pv(
    const bf16_t* __restrict__ qg, const bf16_t* __restrict__ kg,
    const bf16_t* __restrict__ vt, const float* __restrict__ rsg,
    float* __restrict__ pout, bf16_t* __restrict__ ctxo) {
  __shared__ __align__(16) bf16_t Ksh[2][32 * 256];   // 2 x 16KB
  __shared__ __align__(16) bf16_t Vsh[2][256 * 32];   // 2 x 16KB (V^T tile)
  __shared__ __align__(16) bf16_t Psh[2][64 * 32];    // 2 x 4KB
  int bx = blockIdx.x;
  int bh = bx & 15;
  int qt = (bx < 256) ? (31 - (bx >> 4)) : ((bx - 256) >> 4);
  int qbase = qt * 64;
  int nkt = 2 * (qt + 1);    // TK=32 tiles

  int tid = threadIdx.x, w = tid >> 6, l = tid & 63;
  int l15 = l & 15, lhi = l >> 4;
  int wm = w >> 1, wn = w & 1;
  const bf16_t* Q  = qg + (size_t)bh * 2048 * 256;
  const bf16_t* K  = kg + (size_t)bh * 2048 * 256;
  const bf16_t* Vt = vt + (size_t)bh * 256 * 2048;

  // Q fragments: rows qbase + wm*32 + m*16 + l15
  bf16x8 qf[2][8];
#pragma unroll
  for (int m = 0; m < 2; ++m)
#pragma unroll
    for (int ks = 0; ks < 8; ++ks)
      qf[m][ks] = *(const bf16x8*)(Q + (size_t)(qbase + wm * 32 + m * 16 + l15) * 256 + ks * 32 + lhi * 8);

  // inverse rowsums for this lane's 8 rows
  float inv4[2][4];
#pragma unroll
  for (int m = 0; m < 2; ++m)
#pragma unroll
    for (int j = 0; j < 4; ++j)
      inv4[m][j] = rsg[(size_t)bh * 2048 + qbase + wm * 32 + m * 16 + lhi * 4 + j];

  // K+V staging (R5-proven): 8 gload_lds per stage (4K + 4V)
#define PSTAGE(t_) do {                                                         \
    char* kd = (char*)Ksh[(t_) & 1] + w * 1024;                                 \
    char* vd = (char*)Vsh[(t_) & 1] + w * 1024;                                 \
    _Pragma("unroll")                                                           \
    for (int j = 0; j < 4; ++j) {                                               \
      int idx = (j * 256 + tid) * 16;                                           \
      { int r = idx >> 9; int co = (idx & 511) ^ ((r & 7) << 4);                \
        gload16(K + (size_t)((t_) * 32 + r) * 256 + (co >> 1), kd + j * 4096); }\
      { int r = idx >> 6; int co = (idx & 63) ^ (((r >> 2) & 3) << 4);          \
        gload16(Vt + (size_t)r * 2048 + (t_) * 32 + (co >> 1), vd + j * 4096); }\
    } } while (0)

  PSTAGE(0);
  asm volatile("s_waitcnt vmcnt(0)" ::: "memory");
  __builtin_amdgcn_s_barrier();

  int krow = wn * 16 + l15;
  f32x4 ctx[4][4] = {};
  for (int t = 0; t < nkt; ++t) {
    const char* Kb = (const char*)Ksh[t & 1];
    const char* Vb = (const char*)Vsh[t & 1];
    char* Pb = (char*)Psh[t & 1];

    // QK: rows [wm*32,+32) x cols [wn*16,+16)
    f32x4 acc[2] = {};
    __builtin_amdgcn_s_setprio(1);
#pragma unroll
    for (int ks = 0; ks < 8; ++ks) {
      bf16x8 kb = *(const bf16x8*)(Kb + krow * 512 + ((ks * 64 + lhi * 16) ^ ((krow & 7) << 4)));
      acc[0] = mfma16(qf[0][ks], kb, acc[0]);
      acc[1] = mfma16(qf[1][ks], kb, acc[1]);
    }
    __builtin_amdgcn_s_setprio(0);

    // exp/normalize/mask; keep in regs for dump; write bf16 to Psh[t&1]
    float ev[2][4];
#pragma unroll
    for (int m = 0; m < 2; ++m)
#pragma unroll
      for (int j = 0; j < 4; ++j) {
        int rr = wm * 32 + m * 16 + lhi * 4 + j;
        int qr = qbase + rr;
        int kc = t * 32 + krow;
        float e = (kc <= qr) ? __expf(acc[m][j] * 0.0625f) * inv4[m][j] : 0.f;
        ev[m][j] = e;
        int addr = rr * 64 + krow * 2;
        *(bf16_t*)((char*)Pb + (addr ^ (((rr >> 2) & 3) << 4))) = (bf16_t)e;
      }
    asm volatile("s_waitcnt lgkmcnt(0)" ::: "memory");   // P writes + QK reads drained
    __builtin_amdgcn_s_barrier();                         // BAR1: Psh visible; K/V[t^1] free

    // stage next tile (issued before pout stores so vmcnt(8) retires the stage)
    if (t + 1 < nkt) PSTAGE(t + 1);

    // dump P -> pout directly from registers (f32)
#pragma unroll
    for (int m = 0; m < 2; ++m)
#pragma unroll
      for (int j = 0; j < 4; ++j) {
        int rr = wm * 32 + m * 16 + lhi * 4 + j;
        pout[((size_t)bh * 2048 + qbase + rr) * 2048 + t * 32 + krow] = ev[m][j];
      }

    // PV: all 64 P rows x this wave's d-cols [w*64,+64)
    bf16x8 pa[4], vb[4];
#pragma unroll
    for (int m4 = 0; m4 < 4; ++m4) {
      int pr = m4 * 16 + l15;
      pa[m4] = *(const bf16x8*)((const char*)Pb + ((pr * 64 + lhi * 16) ^ (((pr >> 2) & 3) << 4)));
    }
#pragma unroll
    for (int n = 0; n < 4; ++n) {
      int vr = w * 64 + n * 16 + l15;
      vb[n] = *(const bf16x8*)((const char*)Vb + ((vr * 64 + lhi * 16) ^ (((vr >> 2) & 3) << 4)));
    }
    __builtin_amdgcn_s_setprio(1);
#pragma unroll
    for (int m4 = 0; m4 < 4; ++m4)
#pragma unroll
      for (int n = 0; n < 4; ++n)
        ctx[m4][n] = mfma16(pa[m4], vb[n], ctx[m4][n]);
    __builtin_amdgcn_s_setprio(0);

    asm volatile("s_waitcnt lgkmcnt(0)" ::: "memory");   // PV reads drained
    asm volatile("s_waitcnt vmcnt(8)" ::: "memory");     // stage(t+1) landed (stores float)
    __builtin_amdgcn_s_barrier();                         // BAR2: next tile ready
  }
#undef PSTAGE

  // ctx write: (b, s, h*256 + d) bf16
  int b = bh >> 3, h = bh & 7;
#pragma unroll
  for (int m4 = 0; m4 < 4; ++m4)
#pragma unroll
    for (int n = 0; n < 4; ++n)
#pragma unroll
      for (int j = 0; j < 4; ++j) {
        int qr = qbase + m4 * 16 + lhi * 4 + j;
        ctxo[((size_t)b * 2048 + qr) * 2048 + h * 256 + w * 64 + n * 16 + l15] = (bf16_t)ctx[m4][n][j];
      }

  // zero-fill masked region beyond causal boundary
  int zs = qbase + 64;
  for (int r = 0; r < 64; ++r) {
    size_t base2 = ((size_t)bh * 2048 + qbase + r) * 2048;
    for (int c = zs + tid * 4; c < 2048; c += 1024)
      *(float4*)(pout + base2 + c) = make_float4(0.f, 0.f, 0.f, 0.f);
  }
}

// ---------------- host launch ----------------
extern "C" void kernel_launch(void* const* d_in, const int* in_sizes, int n_in,
                              void* d_out, int out_size, void* d_ws, size_t ws_size,
                              hipStream_t stream) {
  const float* x     = (const float*)d_in[0];
  const float* ln1g  = (const float*)d_in[2];
  const float* ln1b  = (const float*)d_in[3];
  const float* wq_w  = (const float*)d_in[4];
  const float* wq_b  = (const float*)d_in[5];
  const float* wk_w  = (const float*)d_in[6];
  const float* wk_b  = (const float*)d_in[7];
  const float* wv_w  = (const float*)d_in[8];
  const float* wv_b  = (const float*)d_in[9];
  const float* dw    = (const float*)d_in[10];
  const float* db    = (const float*)d_in[11];
  const float* ln2g  = (const float*)d_in[12];
  const float* ln2b  = (const float*)d_in[13];
  const float* f1w   = (const float*)d_in[14];
  const float* f1b   = (const float*)d_in[15];
  const float* f2w   = (const float*)d_in[16];
  const float* f2b   = (const float*)d_in[17];

  char* ws = (char*)d_ws;
  const size_t MB = 1u << 20;
  float*  xn_f = (float*) (ws + 0 * MB);
  bf16_t* xn_b = (bf16_t*)(ws + 4 * MB);
  bf16_t* q_b  = (bf16_t*)(ws + 6 * MB);
  bf16_t* k_b  = (bf16_t*)(ws + 22 * MB);
  bf16_t* ctx_b= (bf16_t*)(ws + 38 * MB);
  bf16_t* vt_b = (bf16_t*)(ws + 54 * MB);
  float*  x1_f = (float*) (ws + 70 * MB);
  bf16_t* m_b  = (bf16_t*)(ws + 74 * MB);
  bf16_t* h_b  = (bf16_t*)(ws + 76 * MB);
  bf16_t* wq_bf = (bf16_t*)(ws + 84 * MB);
  bf16_t* wk_bf = wq_bf + 524288;
  bf16_t* wv_bf = wk_bf + 524288;
  bf16_t* dw_bf = wv_bf + 524288;
  bf16_t* f1_bf = dw_bf + 524288;
  bf16_t* f2_bf = f1_bf + 262144;
  float*  rs_f  = (float*)(ws + 90 * MB);
  float* parts_d = (float*)q_b;
  float* parts_f = (float*)k_b;

  float* out0 = (float*)d_out;
  float* pout = out0 + 1048576;

  k1_lncvt<<<3584, 256, 0, stream>>>(x, ln1g, ln1b, xn_f, xn_b,
                                     wq_w, wk_w, wv_w, dw, f1w, f2w,
                                     wq_bf, wk_bf, wv_bf, dw_bf, f1_bf, f2_bf);

  gemm_qkv<<<dim3(48, 32), 256, 0, stream>>>(xn_b, wq_bf, wk_bf, wv_bf,
                                             wq_b, wk_b, wv_b, q_b, k_b, vt_b);

  rowsum_k<<<512, 256, 0, stream>>>(q_b, k_b, rs_f);

  attn_pv<<<512, 256, 0, stream>>>(q_b, k_b, vt_b, rs_f, pout, ctx_b);

  gemm_part<<<dim3(2, 32, 4), 256, 0, stream>>>(ctx_b, dw_bf, 2048, 512, parts_d);
  reduce_ln<<<1024, 256, 0, stream>>>(parts_d, db, xn_f, ln2g, ln2b, x1_f, m_b);

  gemm_fc1<<<dim3(8, 32), 256, 0, stream>>>(m_b, f1_bf, f1b, h_b);

  gemm_part<<<dim3(2, 32, 4), 256, 0, stream>>>(h_b, f2_bf, 1024, 256, parts_f);
  reduce4<<<1024, 256, 0, stream>>>(parts_f, f2b, x1_f, out0);
}

// Round 12
// 203.462 us; speedup vs baseline: 1.5643x; 1.1068x over previous
//
#include <hip/hip_runtime.h>
#include <hip/hip_bf16.h>

// TransformerLayer on MI355X (gfx950). Round 12:
//  attn_fused2 = R5-exact pass B (3 barriers/tile, 2-deep PSTAGE prefetch,
//  counted vmcnt(8), LDS->f32x4 dump) + rowsum fused as pass A (rowsum_k's
//  exact TK=64 2-deep loop, aliased LDS, sums -> invsh in LDS; no rs_f,
//  one launch instead of two). R11 lesson: prefetch DEPTH (stage t+2 at
//  iter end) is the binding term, not barrier count.
//  GEMM stack byte-identical (proven).

typedef __bf16 bf16_t;
typedef __bf16 bf16x8 __attribute__((ext_vector_type(8)));
typedef __bf16 bf16x4 __attribute__((ext_vector_type(4)));
typedef float  f32x4  __attribute__((ext_vector_type(4)));

#define DEV __device__ __forceinline__

DEV f32x4 mfma16(bf16x8 a, bf16x8 b, f32x4 c) {
  return __builtin_amdgcn_mfma_f32_16x16x32_bf16(a, b, c, 0, 0, 0);
}

DEV void gload16(const void* g, void* l) {
  __builtin_amdgcn_global_load_lds(
      (const __attribute__((address_space(1))) unsigned int*)g,
      (__attribute__((address_space(3))) unsigned int*)l, 16, 0, 0);
}

// ---------------- fused LN1 + weight cvt (grid 1024 + 2560) ----------------
__global__ __launch_bounds__(256) void k1_lncvt(
    const float* __restrict__ x, const float* __restrict__ g, const float* __restrict__ bta,
    float* __restrict__ of, bf16_t* __restrict__ ob,
    const float* __restrict__ s0, const float* __restrict__ s1,
    const float* __restrict__ s2, const float* __restrict__ s3,
    const float* __restrict__ s4, const float* __restrict__ s5,
    bf16_t* __restrict__ d0, bf16_t* __restrict__ d1, bf16_t* __restrict__ d2,
    bf16_t* __restrict__ d3, bf16_t* __restrict__ d4, bf16_t* __restrict__ d5) {
  int bid = blockIdx.x;
  if (bid < 1024) {
    int row = bid * 4 + (threadIdx.x >> 6);
    int l = threadIdx.x & 63;
    const float4 v = *(const float4*)(x + (size_t)row * 256 + l * 4);
    float s  = v.x + v.y + v.z + v.w;
    float s2 = v.x*v.x + v.y*v.y + v.z*v.z + v.w*v.w;
#pragma unroll
    for (int o = 1; o < 64; o <<= 1) { s += __shfl_xor(s, o, 64); s2 += __shfl_xor(s2, o, 64); }
    float m   = s * (1.f/256.f);
    float var = s2 * (1.f/256.f) - m * m;
    float rs  = rsqrtf(var + 1e-9f);
    const float4 gv = *(const float4*)(g   + l * 4);
    const float4 bv = *(const float4*)(bta + l * 4);
    float4 y;
    y.x = (v.x - m) * rs * gv.x + bv.x;
    y.y = (v.y - m) * rs * gv.y + bv.y;
    y.z = (v.z - m) * rs * gv.z + bv.z;
    y.w = (v.w - m) * rs * gv.w + bv.w;
    *(float4*)(of + (size_t)row * 256 + l * 4) = y;
    bf16x4 yb = { (bf16_t)y.x, (bf16_t)y.y, (bf16_t)y.z, (bf16_t)y.w };
    *(bf16x4*)(ob + (size_t)row * 256 + l * 4) = yb;
  } else {
    int i = (bid - 1024) * 256 + threadIdx.x;
    const float* s; bf16_t* d; int off;
    if      (i < 131072) { s = s0; d = d0; off = i; }
    else if (i < 262144) { s = s1; d = d1; off = i - 131072; }
    else if (i < 393216) { s = s2; d = d2; off = i - 262144; }
    else if (i < 524288) { s = s3; d = d3; off = i - 393216; }
    else if (i < 589824) { s = s4; d = d4; off = i - 524288; }
    else                 { s = s5; d = d5; off = i - 589824; }
    float4 v = ((const float4*)s)[off];
    bf16x4 o = { (bf16_t)v.x, (bf16_t)v.y, (bf16_t)v.z, (bf16_t)v.w };
    ((bf16x4*)d)[off] = o;
  }
}

// ---------------- 2-phase double-buffered 128x128 GEMM core ----------------
DEV void gemm_core(const bf16_t* __restrict__ A, const bf16_t* __restrict__ W,
                   int lda, int row0, int col0, int k0, int kiters,
                   char* Asb, char* Bsb, f32x4 (&acc)[4][4]) {
  int tid = threadIdx.x, w = tid >> 6, l = tid & 63, l15 = l & 15, lhi = l >> 4;
  int wr = (w >> 1) * 64, wc = (w & 1) * 64;

#define STAGE(buf, kk) do {                                                   \
    char* Ad = Asb + (buf) * 8192 + w * 1024;                                 \
    char* Bd = Bsb + (buf) * 8192 + w * 1024;                                 \
    _Pragma("unroll")                                                         \
    for (int j = 0; j < 2; ++j) {                                             \
      int idx = (j * 256 + tid) * 8; int r = idx >> 5, c = idx & 31;          \
      gload16(A + (size_t)(row0 + r) * lda + (kk) + c, Ad + j * 4096);        \
      gload16(W + (size_t)(col0 + r) * lda + (kk) + c, Bd + j * 4096);        \
    } } while (0)

  STAGE(0, k0);
  for (int t = 0; t < kiters; ++t) {
    int cur = t & 1;
    if (t + 1 < kiters) {
      STAGE(cur ^ 1, k0 + (t + 1) * 32);
      asm volatile("s_waitcnt vmcnt(4)" ::: "memory");
    } else {
      asm volatile("s_waitcnt vmcnt(0)" ::: "memory");
    }
    __builtin_amdgcn_s_barrier();
    asm volatile("" ::: "memory");
    const bf16_t* As = (const bf16_t*)(Asb + cur * 8192);
    const bf16_t* Bs = (const bf16_t*)(Bsb + cur * 8192);
    bf16x8 af[4], bfr[4];
#pragma unroll
    for (int m = 0; m < 4; ++m)
      af[m] = *(const bf16x8*)(As + (wr + 16 * m + l15) * 32 + lhi * 8);
#pragma unroll
    for (int n = 0; n < 4; ++n)
      bfr[n] = *(const bf16x8*)(Bs + (wc + 16 * n + l15) * 32 + lhi * 8);
#pragma unroll
    for (int m = 0; m < 4; ++m)
#pragma unroll
      for (int n = 0; n < 4; ++n)
        acc[m][n] = mfma16(af[m], bfr[n], acc[m][n]);
    asm volatile("s_waitcnt lgkmcnt(0)" ::: "memory");
    __builtin_amdgcn_s_barrier();
  }
#undef STAGE
}

// ---------------- fused QKV: grid (48, 32); V writes V^T via LDS transpose ----------------
__global__ __launch_bounds__(256, 4) void gemm_qkv(
    const bf16_t* __restrict__ A,
    const bf16_t* __restrict__ W0, const bf16_t* __restrict__ W1, const bf16_t* __restrict__ W2,
    const float* __restrict__ b0, const float* __restrict__ b1, const float* __restrict__ b2,
    bf16_t* __restrict__ qo, bf16_t* __restrict__ ko, bf16_t* __restrict__ vto) {
  __shared__ char smem[34816];   // staging 32KB | V-transpose 128x136 bf16
  char* Asb = smem;
  char* Bsb = smem + 16384;
  int bx = blockIdx.x;
  int wsel = bx >> 4, cb = bx & 15;
  const bf16_t* W    = wsel == 0 ? W0 : (wsel == 1 ? W1 : W2);
  const float*  bias = wsel == 0 ? b0 : (wsel == 1 ? b1 : b2);
  int row0 = blockIdx.y * 128, col0 = cb * 128;
  f32x4 acc[4][4] = {};
  gemm_core(A, W, 256, row0, col0, 0, 8, Asb, Bsb, acc);

  int tid = threadIdx.x, w = tid >> 6, l = tid & 63, l15 = l & 15, lhi = l >> 4;
  int wr = (w >> 1) * 64, wc = (w & 1) * 64;

  if (wsel < 2) {
    bf16_t* out = wsel == 0 ? qo : ko;
#pragma unroll
    for (int m = 0; m < 4; ++m)
#pragma unroll
      for (int n = 0; n < 4; ++n)
#pragma unroll
        for (int j = 0; j < 4; ++j) {
          int row = row0 + wr + 16 * m + lhi * 4 + j;
          int col = col0 + wc + 16 * n + l15;
          float v = acc[m][n][j] + bias[col];
          out[((size_t)((row >> 11) * 8 + (col >> 8)) * 2048 + (row & 2047)) * 256 + (col & 255)] = (bf16_t)v;
        }
  } else {
    // V: transpose in LDS, write V^T (B,H,Dh,S)
    __syncthreads();   // full drain before overwriting staging LDS
    bf16_t* T = (bf16_t*)smem;   // [128 d][136 stride] bf16
#pragma unroll
    for (int m = 0; m < 4; ++m)
#pragma unroll
      for (int n = 0; n < 4; ++n) {
        int d = wc + 16 * n + l15;
        int s = wr + 16 * m + lhi * 4;
        bf16x4 v4;
#pragma unroll
        for (int j = 0; j < 4; ++j) v4[j] = (bf16_t)(acc[m][n][j] + bias[col0 + d]);
        *(bf16x4*)(T + d * 136 + s) = v4;
      }
    __syncthreads();
    int bh = ((row0 >> 11) << 3) + (col0 >> 8);
    int d0 = col0 & 255, s0g = row0 & 2047;
#pragma unroll
    for (int p = 0; p < 8; ++p) {
      int idx = p * 256 + tid;
      int d = idx >> 4, c = (idx & 15) * 8;
      bf16x8 v8 = *(const bf16x8*)(T + d * 136 + c);
      *(bf16x8*)(vto + ((size_t)bh * 256 + d0 + d) * 2048 + s0g + c) = v8;
    }
  }
}

// ---------------- split-K partial GEMM: N=256, grid (2, 32, 4) ----------------
__global__ __launch_bounds__(256, 4) void gemm_part(
    const bf16_t* __restrict__ A, const bf16_t* __restrict__ W,
    int lda, int ksub, float* __restrict__ parts) {
  __shared__ char Asb[2 * 8192];
  __shared__ char Bsb[2 * 8192];
  int z = blockIdx.z;
  int row0 = blockIdx.y * 128, col0 = blockIdx.x * 128;
  f32x4 acc[4][4] = {};
  gemm_core(A, W, lda, row0, col0, z * ksub, ksub >> 5, Asb, Bsb, acc);

  int tid = threadIdx.x, w = tid >> 6, l = tid & 63, l15 = l & 15, lhi = l >> 4;
  int wr = (w >> 1) * 64, wc = (w & 1) * 64;
  float* p = parts + (size_t)z * 1048576;
#pragma unroll
  for (int m = 0; m < 4; ++m)
#pragma unroll
    for (int n = 0; n < 4; ++n)
#pragma unroll
      for (int j = 0; j < 4; ++j) {
        int row = row0 + wr + 16 * m + lhi * 4 + j;
        int col = col0 + wc + 16 * n + l15;
        p[(size_t)row * 256 + col] = acc[m][n][j];
      }
}

// ---------------- reduce 4 partials + bias + residual (final out) ----------------
__global__ __launch_bounds__(256) void reduce4(
    const float* __restrict__ parts, const float* __restrict__ bias,
    const float* __restrict__ res, float* __restrict__ out) {
  int i = blockIdx.x * 256 + threadIdx.x;
  f32x4 s = *(const f32x4*)(parts + (size_t)i * 4);
  s += *(const f32x4*)(parts + 1048576 + (size_t)i * 4);
  s += *(const f32x4*)(parts + 2097152 + (size_t)i * 4);
  s += *(const f32x4*)(parts + 3145728 + (size_t)i * 4);
  s += *(const f32x4*)(res + (size_t)i * 4);
  s += *(const f32x4*)(bias + (i & 63) * 4);
  *(f32x4*)(out + (size_t)i * 4) = s;
}

// ---------------- fused dense-reduce + residual + LN2 ----------------
__global__ __launch_bounds__(256) void reduce_ln(
    const float* __restrict__ parts, const float* __restrict__ bias,
    const float* __restrict__ res, const float* __restrict__ g,
    const float* __restrict__ bta, float* __restrict__ x1o, bf16_t* __restrict__ mo) {
  int row = blockIdx.x * 4 + (threadIdx.x >> 6);
  int l = threadIdx.x & 63;
  size_t base = (size_t)row * 256 + l * 4;
  f32x4 s = *(const f32x4*)(parts + base);
  s += *(const f32x4*)(parts + 1048576 + base);
  s += *(const f32x4*)(parts + 2097152 + base);
  s += *(const f32x4*)(parts + 3145728 + base);
  s += *(const f32x4*)(res + base);
  s += *(const f32x4*)(bias + l * 4);
  *(f32x4*)(x1o + base) = s;
  float sm = s[0] + s[1] + s[2] + s[3];
  float s2 = s[0]*s[0] + s[1]*s[1] + s[2]*s[2] + s[3]*s[3];
#pragma unroll
  for (int o = 1; o < 64; o <<= 1) { sm += __shfl_xor(sm, o, 64); s2 += __shfl_xor(s2, o, 64); }
  float m   = sm * (1.f/256.f);
  float var = s2 * (1.f/256.f) - m * m;
  float rs  = rsqrtf(var + 1e-9f);
  const float4 gv = *(const float4*)(g   + l * 4);
  const float4 bv = *(const float4*)(bta + l * 4);
  bf16x4 yb;
  yb[0] = (bf16_t)((s[0] - m) * rs * gv.x + bv.x);
  yb[1] = (bf16_t)((s[1] - m) * rs * gv.y + bv.y);
  yb[2] = (bf16_t)((s[2] - m) * rs * gv.z + bv.z);
  yb[3] = (bf16_t)((s[3] - m) * rs * gv.w + bv.w);
  *(bf16x4*)(mo + base) = yb;
}

// ---------------- FC1 with gelu ----------------
__global__ __launch_bounds__(256, 4) void gemm_fc1(
    const bf16_t* __restrict__ A, const bf16_t* __restrict__ W,
    const float* __restrict__ bias, bf16_t* __restrict__ out) {
  __shared__ char Asb[2 * 8192];
  __shared__ char Bsb[2 * 8192];
  int row0 = blockIdx.y * 128, col0 = blockIdx.x * 128;
  f32x4 acc[4][4] = {};
  gemm_core(A, W, 256, row0, col0, 0, 8, Asb, Bsb, acc);

  int tid = threadIdx.x, w = tid >> 6, l = tid & 63, l15 = l & 15, lhi = l >> 4;
  int wr = (w >> 1) * 64, wc = (w & 1) * 64;
#pragma unroll
  for (int m = 0; m < 4; ++m)
#pragma unroll
    for (int n = 0; n < 4; ++n)
#pragma unroll
      for (int j = 0; j < 4; ++j) {
        int row = row0 + wr + 16 * m + lhi * 4 + j;
        int col = col0 + wc + 16 * n + l15;
        float t = acc[m][n][j] + bias[col];
        float ge = 0.5f * t * (1.f + tanhf(0.7978845608f * t * (1.f + 0.044715f * t * t)));
        out[(size_t)row * 1024 + col] = (bf16_t)ge;
      }
}

// ---------------- attn_fused2: pass A rowsum (TK=64) + pass B P/PV (TK=32) --
// grid 512: bh = bx&15; bx<256: qt=31-(bx>>4) (big first); else qt=(bx-256)>>4.
// Per-CU block pairs (i, i+256) have qt_a+qt_b = 31 -> balanced.
__global__ __launch_bounds__(256, 2) void attn_fused2(
    const bf16_t* __restrict__ qg, const bf16_t* __restrict__ kg,
    const bf16_t* __restrict__ vt, float* __restrict__ pout,
    bf16_t* __restrict__ ctxo) {
  __shared__ __align__(16) char smem[70400];
  // pass A: KA dbuf 2x32KB = smem[0..65536)
  // pass B: Ksh 2x16KB = smem[0..32768), Vsh 2x16KB = smem[32768..65536),
  //         Psh 4KB = smem[65536..69632)
  // sl 512B @69632, invsh 256B @70144 (outside aliased region)
  char*  KA    = smem;
  char*  KB2   = smem;
  char*  VB2   = smem + 32768;
  char*  Psh   = smem + 65536;
  float* sl    = (float*)(smem + 69632);
  float* invsh = (float*)(smem + 70144);

  int bx = blockIdx.x;
  int bh = bx & 15;
  int qt = (bx < 256) ? (31 - (bx >> 4)) : ((bx - 256) >> 4);
  int qbase = qt * 64;

  int tid = threadIdx.x, w = tid >> 6, l = tid & 63;
  int l15 = l & 15, lhi = l >> 4;
  int wm = w >> 1, wn = w & 1;
  const bf16_t* Q  = qg + (size_t)bh * 2048 * 256;
  const bf16_t* K  = kg + (size_t)bh * 2048 * 256;
  const bf16_t* Vt = vt + (size_t)bh * 256 * 2048;

  // Q fragments (used by both passes): rows qbase + wm*32 + m*16 + l15
  bf16x8 qf[2][8];
#pragma unroll
  for (int m = 0; m < 2; ++m)
#pragma unroll
    for (int ks = 0; ks < 8; ++ks)
      qf[m][ks] = *(const bf16x8*)(Q + (size_t)(qbase + wm * 32 + m * 16 + l15) * 256 + ks * 32 + lhi * 8);

  // ================= pass A: masked exp rowsums (rowsum_k structure) ========
  int nktA = qt + 1;
#define RSTAGE(t_) do {                                                        \
    char* dst = KA + ((t_) & 1) * 32768 + w * 1024;                            \
    _Pragma("unroll")                                                          \
    for (int j = 0; j < 8; ++j) {                                              \
      int idx = (j * 256 + tid) * 16; int r = idx >> 9;                        \
      int co = (idx & 511) ^ ((r & 7) << 4);                                   \
      gload16(K + (size_t)((t_) * 64 + r) * 256 + (co >> 1), dst + j * 4096);  \
    } } while (0)

  RSTAGE(0);
  if (nktA > 1) RSTAGE(1);

  float sums[2][4] = {};
  for (int t = 0; t < nktA; ++t) {
    if (t + 1 < nktA) asm volatile("s_waitcnt vmcnt(8)" ::: "memory");
    else              asm volatile("s_waitcnt vmcnt(0)" ::: "memory");
    __builtin_amdgcn_s_barrier();
    const char* Kb = KA + (t & 1) * 32768;
    f32x4 acc[2][2] = {};
    __builtin_amdgcn_s_setprio(1);
#pragma unroll
    for (int ks = 0; ks < 8; ++ks) {
#pragma unroll
      for (int n2 = 0; n2 < 2; ++n2) {
        int row = wn * 32 + n2 * 16 + l15;
        bf16x8 kb = *(const bf16x8*)(Kb + row * 512 + ((ks * 64 + lhi * 16) ^ ((row & 7) << 4)));
#pragma unroll
        for (int m = 0; m < 2; ++m)
          acc[m][n2] = mfma16(qf[m][ks], kb, acc[m][n2]);
      }
    }
    __builtin_amdgcn_s_setprio(0);
#pragma unroll
    for (int m = 0; m < 2; ++m)
#pragma unroll
      for (int n2 = 0; n2 < 2; ++n2)
#pragma unroll
        for (int j = 0; j < 4; ++j) {
          int qr = qbase + wm * 32 + m * 16 + lhi * 4 + j;
          int kc = t * 64 + wn * 32 + n2 * 16 + l15;
          sums[m][j] += (kc <= qr) ? __expf(acc[m][n2][j] * 0.0625f) : 0.f;
        }
    asm volatile("s_waitcnt lgkmcnt(0)" ::: "memory");
    __builtin_amdgcn_s_barrier();
    if (t + 2 < nktA) RSTAGE(t + 2);
  }
#undef RSTAGE

#pragma unroll
  for (int m = 0; m < 2; ++m)
#pragma unroll
    for (int j = 0; j < 4; ++j)
#pragma unroll
      for (int o = 1; o < 16; o <<= 1)
        sums[m][j] += __shfl_xor(sums[m][j], o, 64);
  if (l15 == 0)
#pragma unroll
    for (int m = 0; m < 2; ++m)
#pragma unroll
      for (int j = 0; j < 4; ++j)
        sl[wn * 64 + wm * 32 + m * 16 + lhi * 4 + j] = sums[m][j];
  __syncthreads();
  if (tid < 64) invsh[tid] = 1.f / (sl[tid] + sl[64 + tid]);
  __syncthreads();
  float inv4[2][4];
#pragma unroll
  for (int m = 0; m < 2; ++m)
#pragma unroll
    for (int j = 0; j < 4; ++j)
      inv4[m][j] = invsh[wm * 32 + m * 16 + lhi * 4 + j];
  __syncthreads();   // all invsh reads done before KA region reuse

  // ================= pass B: R5-exact P-write + PV, TK=32 ====================
  int nktB = 2 * (qt + 1);
#define PSTAGE(t_) do {                                                         \
    char* kd = KB2 + ((t_) & 1) * 16384 + w * 1024;                             \
    char* vd = VB2 + ((t_) & 1) * 16384 + w * 1024;                             \
    _Pragma("unroll")                                                           \
    for (int j = 0; j < 4; ++j) {                                               \
      int idx = (j * 256 + tid) * 16;                                           \
      { int r = idx >> 9; int co = (idx & 511) ^ ((r & 7) << 4);                \
        gload16(K + (size_t)((t_) * 32 + r) * 256 + (co >> 1), kd + j * 4096); }\
      { int r = idx >> 6; int co = (idx & 63) ^ (((r >> 2) & 3) << 4);          \
        gload16(Vt + (size_t)r * 2048 + (t_) * 32 + (co >> 1), vd + j * 4096); }\
    } } while (0)

  PSTAGE(0);
  PSTAGE(1);

  int krow = wn * 16 + l15;
  f32x4 ctx[4][4] = {};
  for (int t = 0; t < nktB; ++t) {
    if (t + 1 < nktB) asm volatile("s_waitcnt vmcnt(8)" ::: "memory");
    else              asm volatile("s_waitcnt vmcnt(0)" ::: "memory");
    __builtin_amdgcn_s_barrier();
    const char* Kb = KB2 + (t & 1) * 16384;
    const char* Vb = VB2 + (t & 1) * 16384;

    // QK: rows [wm*32,+32) x cols [wn*16,+16)
    f32x4 acc[2] = {};
    __builtin_amdgcn_s_setprio(1);
#pragma unroll
    for (int ks = 0; ks < 8; ++ks) {
      bf16x8 kb = *(const bf16x8*)(Kb + krow * 512 + ((ks * 64 + lhi * 16) ^ ((krow & 7) << 4)));
      acc[0] = mfma16(qf[0][ks], kb, acc[0]);
      acc[1] = mfma16(qf[1][ks], kb, acc[1]);
    }
    __builtin_amdgcn_s_setprio(0);

    // exp/normalize/mask -> Psh (bf16, swz ((rr>>2)&3)<<4)
#pragma unroll
    for (int m = 0; m < 2; ++m)
#pragma unroll
      for (int j = 0; j < 4; ++j) {
        int rr = wm * 32 + m * 16 + lhi * 4 + j;
        int qr = qbase + rr;
        int kc = t * 32 + krow;
        float e = (kc <= qr) ? __expf(acc[m][j] * 0.0625f) * inv4[m][j] : 0.f;
        int addr = rr * 64 + krow * 2;
        *(bf16_t*)(Psh + (addr ^ (((rr >> 2) & 3) << 4))) = (bf16_t)e;
      }
    asm volatile("s_waitcnt lgkmcnt(0)" ::: "memory");   // P writes visible
    __builtin_amdgcn_s_barrier();

    // dump Psh -> pout as f32 (coalesced f32x4)
    {
      int row = tid >> 2;
      int ch  = (tid & 3) * 16;
      bf16x8 p8 = *(const bf16x8*)(Psh + row * 64 + (ch ^ (((row >> 2) & 3) << 4)));
      float* dst = pout + ((size_t)bh * 2048 + qbase + row) * 2048 + t * 32 + (tid & 3) * 8;
      f32x4 lo = { (float)p8[0], (float)p8[1], (float)p8[2], (float)p8[3] };
      f32x4 hi = { (float)p8[4], (float)p8[5], (float)p8[6], (float)p8[7] };
      *(f32x4*)dst = lo;
      *(f32x4*)(dst + 4) = hi;
    }

    // PV: all 64 P rows x this wave's d-cols [w*64,+64)
    bf16x8 pa[4], vb[4];
#pragma unroll
    for (int m4 = 0; m4 < 4; ++m4) {
      int pr = m4 * 16 + l15;
      pa[m4] = *(const bf16x8*)(Psh + ((pr * 64 + lhi * 16) ^ (((pr >> 2) & 3) << 4)));
    }
#pragma unroll
    for (int n = 0; n < 4; ++n) {
      int vr = w * 64 + n * 16 + l15;
      vb[n] = *(const bf16x8*)(Vb + ((vr * 64 + lhi * 16) ^ (((vr >> 2) & 3) << 4)));
    }
    __builtin_amdgcn_s_setprio(1);
#pragma unroll
    for (int m4 = 0; m4 < 4; ++m4)
#pragma unroll
      for (int n = 0; n < 4; ++n)
        ctx[m4][n] = mfma16(pa[m4], vb[n], ctx[m4][n]);
    __builtin_amdgcn_s_setprio(0);

    asm volatile("s_waitcnt lgkmcnt(0)" ::: "memory");   // Psh/Vsh reads drained
    __builtin_amdgcn_s_barrier();
    if (t + 2 < nktB) PSTAGE(t + 2);                      // 2-deep prefetch
  }
#undef PSTAGE

  // ctx write: (b, s, h*256 + d) bf16
  int b = bh >> 3, h = bh & 7;
#pragma unroll
  for (int m4 = 0; m4 < 4; ++m4)
#pragma unroll
    for (int n = 0; n < 4; ++n)
#pragma unroll
      for (int j = 0; j < 4; ++j) {
        int qr = qbase + m4 * 16 + lhi * 4 + j;
        ctxo[((size_t)b * 2048 + qr) * 2048 + h * 256 + w * 64 + n * 16 + l15] = (bf16_t)ctx[m4][n][j];
      }

  // zero-fill masked region beyond causal boundary
  int zs = qbase + 64;
  for (int r = 0; r < 64; ++r) {
    size_t base2 = ((size_t)bh * 2048 + qbase + r) * 2048;
    for (int c = zs + tid * 4; c < 2048; c += 1024)
      *(float4*)(pout + base2 + c) = make_float4(0.f, 0.f, 0.f, 0.f);
  }
}

// ---------------- host launch ----------------
extern "C" void kernel_launch(void* const* d_in, const int* in_sizes, int n_in,
                              void* d_out, int out_size, void* d_ws, size_t ws_size,
                              hipStream_t stream) {
  const float* x     = (const float*)d_in[0];
  const float* ln1g  = (const float*)d_in[2];
  const float* ln1b  = (const float*)d_in[3];
  const float* wq_w  = (const float*)d_in[4];
  const float* wq_b  = (const float*)d_in[5];
  const float* wk_w  = (const float*)d_in[6];
  const float* wk_b  = (const float*)d_in[7];
  const float* wv_w  = (const float*)d_in[8];
  const float* wv_b  = (const float*)d_in[9];
  const float* dw    = (const float*)d_in[10];
  const float* db    = (const float*)d_in[11];
  const float* ln2g  = (const float*)d_in[12];
  const float* ln2b  = (const float*)d_in[13];
  const float* f1w   = (const float*)d_in[14];
  const float* f1b   = (const float*)d_in[15];
  const float* f2w   = (const float*)d_in[16];
  const float* f2b   = (const float*)d_in[17];

  char* ws = (char*)d_ws;
  const size_t MB = 1u << 20;
  float*  xn_f = (float*) (ws + 0 * MB);
  bf16_t* xn_b = (bf16_t*)(ws + 4 * MB);
  bf16_t* q_b  = (bf16_t*)(ws + 6 * MB);
  bf16_t* k_b  = (bf16_t*)(ws + 22 * MB);
  bf16_t* ctx_b= (bf16_t*)(ws + 38 * MB);
  bf16_t* vt_b = (bf16_t*)(ws + 54 * MB);
  float*  x1_f = (float*) (ws + 70 * MB);
  bf16_t* m_b  = (bf16_t*)(ws + 74 * MB);
  bf16_t* h_b  = (bf16_t*)(ws + 76 * MB);
  bf16_t* wq_bf = (bf16_t*)(ws + 84 * MB);
  bf16_t* wk_bf = wq_bf + 524288;
  bf16_t* wv_bf = wk_bf + 524288;
  bf16_t* dw_bf = wv_bf + 524288;
  bf16_t* f1_bf = dw_bf + 524288;
  bf16_t* f2_bf = f1_bf + 262144;
  float* parts_d = (float*)q_b;
  float* parts_f = (float*)k_b;

  float* out0 = (float*)d_out;
  float* pout = out0 + 1048576;

  k1_lncvt<<<3584, 256, 0, stream>>>(x, ln1g, ln1b, xn_f, xn_b,
                                     wq_w, wk_w, wv_w, dw, f1w, f2w,
                                     wq_bf, wk_bf, wv_bf, dw_bf, f1_bf, f2_bf);

  gemm_qkv<<<dim3(48, 32), 256, 0, stream>>>(xn_b, wq_bf, wk_bf, wv_bf,
                                             wq_b, wk_b, wv_b, q_b, k_b, vt_b);

  attn_fused2<<<512, 256, 0, stream>>>(q_b, k_b, vt_b, pout, ctx_b);

  gemm_part<<<dim3(2, 32, 4), 256, 0, stream>>>(ctx_b, dw_bf, 2048, 512, parts_d);
  reduce_ln<<<1024, 256, 0, stream>>>(parts_d, db, xn_f, ln2g, ln2b, x1_f, m_b);

  gemm_fc1<<<dim3(8, 32), 256, 0, stream>>>(m_b, f1_bf, f1b, h_b);

  gemm_part<<<dim3(2, 32, 4), 256, 0, stream>>>(h_b, f2_bf, 1024, 256, parts_f);
  reduce4<<<1024, 256, 0, stream>>>(parts_f, f2b, x1_f, out0);
}

// Round 13
// 201.537 us; speedup vs baseline: 1.5793x; 1.0096x over previous
//
#include <hip/hip_runtime.h>
#include <hip/hip_bf16.h>

// TransformerLayer on MI355X (gfx950). Round 13 = R12 + counted-wait audit:
//  - pass B vmcnt(8) -> vmcnt(10) steady-state: the old wait retired the
//    previous tile's 2 pout stores (268MB HBM write stream drain) on every
//    tile's critical path. vmcnt(10) retires exactly PSTAGE(t) (8 loads).
//    t=0 -> 8 (no dump in flight); last tile -> 2.
//  - PSTAGE(0/1) hoisted before the rowsum reduction (overlaps 3 syncthreads
//    + shuffle reduce with the first K/V loads; staging region free after
//    pass A's final barrier).
//  Everything else byte-identical to R12 (203.5us, best).

typedef __bf16 bf16_t;
typedef __bf16 bf16x8 __attribute__((ext_vector_type(8)));
typedef __bf16 bf16x4 __attribute__((ext_vector_type(4)));
typedef float  f32x4  __attribute__((ext_vector_type(4)));

#define DEV __device__ __forceinline__

DEV f32x4 mfma16(bf16x8 a, bf16x8 b, f32x4 c) {
  return __builtin_amdgcn_mfma_f32_16x16x32_bf16(a, b, c, 0, 0, 0);
}

DEV void gload16(const void* g, void* l) {
  __builtin_amdgcn_global_load_lds(
      (const __attribute__((address_space(1))) unsigned int*)g,
      (__attribute__((address_space(3))) unsigned int*)l, 16, 0, 0);
}

// ---------------- fused LN1 + weight cvt (grid 1024 + 2560) ----------------
__global__ __launch_bounds__(256) void k1_lncvt(
    const float* __restrict__ x, const float* __restrict__ g, const float* __restrict__ bta,
    float* __restrict__ of, bf16_t* __restrict__ ob,
    const float* __restrict__ s0, const float* __restrict__ s1,
    const float* __restrict__ s2, const float* __restrict__ s3,
    const float* __restrict__ s4, const float* __restrict__ s5,
    bf16_t* __restrict__ d0, bf16_t* __restrict__ d1, bf16_t* __restrict__ d2,
    bf16_t* __restrict__ d3, bf16_t* __restrict__ d4, bf16_t* __restrict__ d5) {
  int bid = blockIdx.x;
  if (bid < 1024) {
    int row = bid * 4 + (threadIdx.x >> 6);
    int l = threadIdx.x & 63;
    const float4 v = *(const float4*)(x + (size_t)row * 256 + l * 4);
    float s  = v.x + v.y + v.z + v.w;
    float s2 = v.x*v.x + v.y*v.y + v.z*v.z + v.w*v.w;
#pragma unroll
    for (int o = 1; o < 64; o <<= 1) { s += __shfl_xor(s, o, 64); s2 += __shfl_xor(s2, o, 64); }
    float m   = s * (1.f/256.f);
    float var = s2 * (1.f/256.f) - m * m;
    float rs  = rsqrtf(var + 1e-9f);
    const float4 gv = *(const float4*)(g   + l * 4);
    const float4 bv = *(const float4*)(bta + l * 4);
    float4 y;
    y.x = (v.x - m) * rs * gv.x + bv.x;
    y.y = (v.y - m) * rs * gv.y + bv.y;
    y.z = (v.z - m) * rs * gv.z + bv.z;
    y.w = (v.w - m) * rs * gv.w + bv.w;
    *(float4*)(of + (size_t)row * 256 + l * 4) = y;
    bf16x4 yb = { (bf16_t)y.x, (bf16_t)y.y, (bf16_t)y.z, (bf16_t)y.w };
    *(bf16x4*)(ob + (size_t)row * 256 + l * 4) = yb;
  } else {
    int i = (bid - 1024) * 256 + threadIdx.x;
    const float* s; bf16_t* d; int off;
    if      (i < 131072) { s = s0; d = d0; off = i; }
    else if (i < 262144) { s = s1; d = d1; off = i - 131072; }
    else if (i < 393216) { s = s2; d = d2; off = i - 262144; }
    else if (i < 524288) { s = s3; d = d3; off = i - 393216; }
    else if (i < 589824) { s = s4; d = d4; off = i - 524288; }
    else                 { s = s5; d = d5; off = i - 589824; }
    float4 v = ((const float4*)s)[off];
    bf16x4 o = { (bf16_t)v.x, (bf16_t)v.y, (bf16_t)v.z, (bf16_t)v.w };
    ((bf16x4*)d)[off] = o;
  }
}

// ---------------- 2-phase double-buffered 128x128 GEMM core ----------------
DEV void gemm_core(const bf16_t* __restrict__ A, const bf16_t* __restrict__ W,
                   int lda, int row0, int col0, int k0, int kiters,
                   char* Asb, char* Bsb, f32x4 (&acc)[4][4]) {
  int tid = threadIdx.x, w = tid >> 6, l = tid & 63, l15 = l & 15, lhi = l >> 4;
  int wr = (w >> 1) * 64, wc = (w & 1) * 64;

#define STAGE(buf, kk) do {                                                   \
    char* Ad = Asb + (buf) * 8192 + w * 1024;                                 \
    char* Bd = Bsb + (buf) * 8192 + w * 1024;                                 \
    _Pragma("unroll")                                                         \
    for (int j = 0; j < 2; ++j) {                                             \
      int idx = (j * 256 + tid) * 8; int r = idx >> 5, c = idx & 31;          \
      gload16(A + (size_t)(row0 + r) * lda + (kk) + c, Ad + j * 4096);        \
      gload16(W + (size_t)(col0 + r) * lda + (kk) + c, Bd + j * 4096);        \
    } } while (0)

  STAGE(0, k0);
  for (int t = 0; t < kiters; ++t) {
    int cur = t & 1;
    if (t + 1 < kiters) {
      STAGE(cur ^ 1, k0 + (t + 1) * 32);
      asm volatile("s_waitcnt vmcnt(4)" ::: "memory");
    } else {
      asm volatile("s_waitcnt vmcnt(0)" ::: "memory");
    }
    __builtin_amdgcn_s_barrier();
    asm volatile("" ::: "memory");
    const bf16_t* As = (const bf16_t*)(Asb + cur * 8192);
    const bf16_t* Bs = (const bf16_t*)(Bsb + cur * 8192);
    bf16x8 af[4], bfr[4];
#pragma unroll
    for (int m = 0; m < 4; ++m)
      af[m] = *(const bf16x8*)(As + (wr + 16 * m + l15) * 32 + lhi * 8);
#pragma unroll
    for (int n = 0; n < 4; ++n)
      bfr[n] = *(const bf16x8*)(Bs + (wc + 16 * n + l15) * 32 + lhi * 8);
#pragma unroll
    for (int m = 0; m < 4; ++m)
#pragma unroll
      for (int n = 0; n < 4; ++n)
        acc[m][n] = mfma16(af[m], bfr[n], acc[m][n]);
    asm volatile("s_waitcnt lgkmcnt(0)" ::: "memory");
    __builtin_amdgcn_s_barrier();
  }
#undef STAGE
}

// ---------------- fused QKV: grid (48, 32); V writes V^T via LDS transpose ----------------
__global__ __launch_bounds__(256, 4) void gemm_qkv(
    const bf16_t* __restrict__ A,
    const bf16_t* __restrict__ W0, const bf16_t* __restrict__ W1, const bf16_t* __restrict__ W2,
    const float* __restrict__ b0, const float* __restrict__ b1, const float* __restrict__ b2,
    bf16_t* __restrict__ qo, bf16_t* __restrict__ ko, bf16_t* __restrict__ vto) {
  __shared__ char smem[34816];   // staging 32KB | V-transpose 128x136 bf16
  char* Asb = smem;
  char* Bsb = smem + 16384;
  int bx = blockIdx.x;
  int wsel = bx >> 4, cb = bx & 15;
  const bf16_t* W    = wsel == 0 ? W0 : (wsel == 1 ? W1 : W2);
  const float*  bias = wsel == 0 ? b0 : (wsel == 1 ? b1 : b2);
  int row0 = blockIdx.y * 128, col0 = cb * 128;
  f32x4 acc[4][4] = {};
  gemm_core(A, W, 256, row0, col0, 0, 8, Asb, Bsb, acc);

  int tid = threadIdx.x, w = tid >> 6, l = tid & 63, l15 = l & 15, lhi = l >> 4;
  int wr = (w >> 1) * 64, wc = (w & 1) * 64;

  if (wsel < 2) {
    bf16_t* out = wsel == 0 ? qo : ko;
#pragma unroll
    for (int m = 0; m < 4; ++m)
#pragma unroll
      for (int n = 0; n < 4; ++n)
#pragma unroll
        for (int j = 0; j < 4; ++j) {
          int row = row0 + wr + 16 * m + lhi * 4 + j;
          int col = col0 + wc + 16 * n + l15;
          float v = acc[m][n][j] + bias[col];
          out[((size_t)((row >> 11) * 8 + (col >> 8)) * 2048 + (row & 2047)) * 256 + (col & 255)] = (bf16_t)v;
        }
  } else {
    // V: transpose in LDS, write V^T (B,H,Dh,S)
    __syncthreads();   // full drain before overwriting staging LDS
    bf16_t* T = (bf16_t*)smem;   // [128 d][136 stride] bf16
#pragma unroll
    for (int m = 0; m < 4; ++m)
#pragma unroll
      for (int n = 0; n < 4; ++n) {
        int d = wc + 16 * n + l15;
        int s = wr + 16 * m + lhi * 4;
        bf16x4 v4;
#pragma unroll
        for (int j = 0; j < 4; ++j) v4[j] = (bf16_t)(acc[m][n][j] + bias[col0 + d]);
        *(bf16x4*)(T + d * 136 + s) = v4;
      }
    __syncthreads();
    int bh = ((row0 >> 11) << 3) + (col0 >> 8);
    int d0 = col0 & 255, s0g = row0 & 2047;
#pragma unroll
    for (int p = 0; p < 8; ++p) {
      int idx = p * 256 + tid;
      int d = idx >> 4, c = (idx & 15) * 8;
      bf16x8 v8 = *(const bf16x8*)(T + d * 136 + c);
      *(bf16x8*)(vto + ((size_t)bh * 256 + d0 + d) * 2048 + s0g + c) = v8;
    }
  }
}

// ---------------- split-K partial GEMM: N=256, grid (2, 32, 4) ----------------
__global__ __launch_bounds__(256, 4) void gemm_part(
    const bf16_t* __restrict__ A, const bf16_t* __restrict__ W,
    int lda, int ksub, float* __restrict__ parts) {
  __shared__ char Asb[2 * 8192];
  __shared__ char Bsb[2 * 8192];
  int z = blockIdx.z;
  int row0 = blockIdx.y * 128, col0 = blockIdx.x * 128;
  f32x4 acc[4][4] = {};
  gemm_core(A, W, lda, row0, col0, z * ksub, ksub >> 5, Asb, Bsb, acc);

  int tid = threadIdx.x, w = tid >> 6, l = tid & 63, l15 = l & 15, lhi = l >> 4;
  int wr = (w >> 1) * 64, wc = (w & 1) * 64;
  float* p = parts + (size_t)z * 1048576;
#pragma unroll
  for (int m = 0; m < 4; ++m)
#pragma unroll
    for (int n = 0; n < 4; ++n)
#pragma unroll
      for (int j = 0; j < 4; ++j) {
        int row = row0 + wr + 16 * m + lhi * 4 + j;
        int col = col0 + wc + 16 * n + l15;
        p[(size_t)row * 256 + col] = acc[m][n][j];
      }
}

// ---------------- reduce 4 partials + bias + residual (final out) ----------------
__global__ __launch_bounds__(256) void reduce4(
    const float* __restrict__ parts, const float* __restrict__ bias,
    const float* __restrict__ res, float* __restrict__ out) {
  int i = blockIdx.x * 256 + threadIdx.x;
  f32x4 s = *(const f32x4*)(parts + (size_t)i * 4);
  s += *(const f32x4*)(parts + 1048576 + (size_t)i * 4);
  s += *(const f32x4*)(parts + 2097152 + (size_t)i * 4);
  s += *(const f32x4*)(parts + 3145728 + (size_t)i * 4);
  s += *(const f32x4*)(res + (size_t)i * 4);
  s += *(const f32x4*)(bias + (i & 63) * 4);
  *(f32x4*)(out + (size_t)i * 4) = s;
}

// ---------------- fused dense-reduce + residual + LN2 ----------------
__global__ __launch_bounds__(256) void reduce_ln(
    const float* __restrict__ parts, const float* __restrict__ bias,
    const float* __restrict__ res, const float* __restrict__ g,
    const float* __restrict__ bta, float* __restrict__ x1o, bf16_t* __restrict__ mo) {
  int row = blockIdx.x * 4 + (threadIdx.x >> 6);
  int l = threadIdx.x & 63;
  size_t base = (size_t)row * 256 + l * 4;
  f32x4 s = *(const f32x4*)(parts + base);
  s += *(const f32x4*)(parts + 1048576 + base);
  s += *(const f32x4*)(parts + 2097152 + base);
  s += *(const f32x4*)(parts + 3145728 + base);
  s += *(const f32x4*)(res + base);
  s += *(const f32x4*)(bias + l * 4);
  *(f32x4*)(x1o + base) = s;
  float sm = s[0] + s[1] + s[2] + s[3];
  float s2 = s[0]*s[0] + s[1]*s[1] + s[2]*s[2] + s[3]*s[3];
#pragma unroll
  for (int o = 1; o < 64; o <<= 1) { sm += __shfl_xor(sm, o, 64); s2 += __shfl_xor(s2, o, 64); }
  float m   = sm * (1.f/256.f);
  float var = s2 * (1.f/256.f) - m * m;
  float rs  = rsqrtf(var + 1e-9f);
  const float4 gv = *(const float4*)(g   + l * 4);
  const float4 bv = *(const float4*)(bta + l * 4);
  bf16x4 yb;
  yb[0] = (bf16_t)((s[0] - m) * rs * gv.x + bv.x);
  yb[1] = (bf16_t)((s[1] - m) * rs * gv.y + bv.y);
  yb[2] = (bf16_t)((s[2] - m) * rs * gv.z + bv.z);
  yb[3] = (bf16_t)((s[3] - m) * rs * gv.w + bv.w);
  *(bf16x4*)(mo + base) = yb;
}

// ---------------- FC1 with gelu ----------------
__global__ __launch_bounds__(256, 4) void gemm_fc1(
    const bf16_t* __restrict__ A, const bf16_t* __restrict__ W,
    const float* __restrict__ bias, bf16_t* __restrict__ out) {
  __shared__ char Asb[2 * 8192];
  __shared__ char Bsb[2 * 8192];
  int row0 = blockIdx.y * 128, col0 = blockIdx.x * 128;
  f32x4 acc[4][4] = {};
  gemm_core(A, W, 256, row0, col0, 0, 8, Asb, Bsb, acc);

  int tid = threadIdx.x, w = tid >> 6, l = tid & 63, l15 = l & 15, lhi = l >> 4;
  int wr = (w >> 1) * 64, wc = (w & 1) * 64;
#pragma unroll
  for (int m = 0; m < 4; ++m)
#pragma unroll
    for (int n = 0; n < 4; ++n)
#pragma unroll
      for (int j = 0; j < 4; ++j) {
        int row = row0 + wr + 16 * m + lhi * 4 + j;
        int col = col0 + wc + 16 * n + l15;
        float t = acc[m][n][j] + bias[col];
        float ge = 0.5f * t * (1.f + tanhf(0.7978845608f * t * (1.f + 0.044715f * t * t)));
        out[(size_t)row * 1024 + col] = (bf16_t)ge;
      }
}

// ---------------- attn_fused2: pass A rowsum (TK=64) + pass B P/PV (TK=32) --
// grid 512: bh = bx&15; bx<256: qt=31-(bx>>4) (big first); else qt=(bx-256)>>4.
__global__ __launch_bounds__(256, 2) void attn_fused2(
    const bf16_t* __restrict__ qg, const bf16_t* __restrict__ kg,
    const bf16_t* __restrict__ vt, float* __restrict__ pout,
    bf16_t* __restrict__ ctxo) {
  __shared__ __align__(16) char smem[70400];
  char*  KA    = smem;
  char*  KB2   = smem;
  char*  VB2   = smem + 32768;
  char*  Psh   = smem + 65536;
  float* sl    = (float*)(smem + 69632);
  float* invsh = (float*)(smem + 70144);

  int bx = blockIdx.x;
  int bh = bx & 15;
  int qt = (bx < 256) ? (31 - (bx >> 4)) : ((bx - 256) >> 4);
  int qbase = qt * 64;

  int tid = threadIdx.x, w = tid >> 6, l = tid & 63;
  int l15 = l & 15, lhi = l >> 4;
  int wm = w >> 1, wn = w & 1;
  const bf16_t* Q  = qg + (size_t)bh * 2048 * 256;
  const bf16_t* K  = kg + (size_t)bh * 2048 * 256;
  const bf16_t* Vt = vt + (size_t)bh * 256 * 2048;

  // Q fragments (both passes): rows qbase + wm*32 + m*16 + l15
  bf16x8 qf[2][8];
#pragma unroll
  for (int m = 0; m < 2; ++m)
#pragma unroll
    for (int ks = 0; ks < 8; ++ks)
      qf[m][ks] = *(const bf16x8*)(Q + (size_t)(qbase + wm * 32 + m * 16 + l15) * 256 + ks * 32 + lhi * 8);

  // ================= pass A: masked exp rowsums =================
  int nktA = qt + 1;
#define RSTAGE(t_) do {                                                        \
    char* dst = KA + ((t_) & 1) * 32768 + w * 1024;                            \
    _Pragma("unroll")                                                          \
    for (int j = 0; j < 8; ++j) {                                              \
      int idx = (j * 256 + tid) * 16; int r = idx >> 9;                        \
      int co = (idx & 511) ^ ((r & 7) << 4);                                   \
      gload16(K + (size_t)((t_) * 64 + r) * 256 + (co >> 1), dst + j * 4096);  \
    } } while (0)

  RSTAGE(0);
  if (nktA > 1) RSTAGE(1);

  float sums[2][4] = {};
  for (int t = 0; t < nktA; ++t) {
    if (t + 1 < nktA) asm volatile("s_waitcnt vmcnt(8)" ::: "memory");
    else              asm volatile("s_waitcnt vmcnt(0)" ::: "memory");
    __builtin_amdgcn_s_barrier();
    const char* Kb = KA + (t & 1) * 32768;
    f32x4 acc[2][2] = {};
    __builtin_amdgcn_s_setprio(1);
#pragma unroll
    for (int ks = 0; ks < 8; ++ks) {
#pragma unroll
      for (int n2 = 0; n2 < 2; ++n2) {
        int row = wn * 32 + n2 * 16 + l15;
        bf16x8 kb = *(const bf16x8*)(Kb + row * 512 + ((ks * 64 + lhi * 16) ^ ((row & 7) << 4)));
#pragma unroll
        for (int m = 0; m < 2; ++m)
          acc[m][n2] = mfma16(qf[m][ks], kb, acc[m][n2]);
      }
    }
    __builtin_amdgcn_s_setprio(0);
#pragma unroll
    for (int m = 0; m < 2; ++m)
#pragma unroll
      for (int n2 = 0; n2 < 2; ++n2)
#pragma unroll
        for (int j = 0; j < 4; ++j) {
          int qr = qbase + wm * 32 + m * 16 + lhi * 4 + j;
          int kc = t * 64 + wn * 32 + n2 * 16 + l15;
          sums[m][j] += (kc <= qr) ? __expf(acc[m][n2][j] * 0.0625f) : 0.f;
        }
    asm volatile("s_waitcnt lgkmcnt(0)" ::: "memory");
    __builtin_amdgcn_s_barrier();
    if (t + 2 < nktA) RSTAGE(t + 2);
  }
#undef RSTAGE

  // ---- pass B staging macro (needed early for the hoisted prefetch) ----
#define PSTAGE(t_) do {                                                         \
    char* kd = KB2 + ((t_) & 1) * 16384 + w * 1024;                             \
    char* vd = VB2 + ((t_) & 1) * 16384 + w * 1024;                             \
    _Pragma("unroll")                                                           \
    for (int j = 0; j < 4; ++j) {                                               \
      int idx = (j * 256 + tid) * 16;                                           \
      { int r = idx >> 9; int co = (idx & 511) ^ ((r & 7) << 4);                \
        gload16(K + (size_t)((t_) * 32 + r) * 256 + (co >> 1), kd + j * 4096); }\
      { int r = idx >> 6; int co = (idx & 63) ^ (((r >> 2) & 3) << 4);          \
        gload16(Vt + (size_t)r * 2048 + (t_) * 32 + (co >> 1), vd + j * 4096); }\
    } } while (0)

  // hoisted pass-B prefetch: staging region's last readers drained at the
  // loop's final lgkmcnt(0)+barrier; overlaps the reduction below.
  PSTAGE(0);
  PSTAGE(1);

#pragma unroll
  for (int m = 0; m < 2; ++m)
#pragma unroll
    for (int j = 0; j < 4; ++j)
#pragma unroll
      for (int o = 1; o < 16; o <<= 1)
        sums[m][j] += __shfl_xor(sums[m][j], o, 64);
  if (l15 == 0)
#pragma unroll
    for (int m = 0; m < 2; ++m)
#pragma unroll
      for (int j = 0; j < 4; ++j)
        sl[wn * 64 + wm * 32 + m * 16 + lhi * 4 + j] = sums[m][j];
  __syncthreads();
  if (tid < 64) invsh[tid] = 1.f / (sl[tid] + sl[64 + tid]);
  __syncthreads();
  float inv4[2][4];
#pragma unroll
  for (int m = 0; m < 2; ++m)
#pragma unroll
    for (int j = 0; j < 4; ++j)
      inv4[m][j] = invsh[wm * 32 + m * 16 + lhi * 4 + j];
  __syncthreads();   // all invsh reads done before region reuse

  // ================= pass B: P-write + PV, TK=32, counted vmcnt =============
  int nktB = 2 * (qt + 1);
  int krow = wn * 16 + l15;
  f32x4 ctx[4][4] = {};
  for (int t = 0; t < nktB; ++t) {
    // in-flight (oldest first): PSTAGE(t) 8, dump(t-1) 2 stores, PSTAGE(t+1) 8.
    // Retire exactly PSTAGE(t): t=0 -> vmcnt(8) (no dump yet);
    // last tile -> vmcnt(2) (no PSTAGE(t+1)); else vmcnt(10).
    if (t == 0)               asm volatile("s_waitcnt vmcnt(8)"  ::: "memory");
    else if (t + 1 == nktB)   asm volatile("s_waitcnt vmcnt(2)"  ::: "memory");
    else                      asm volatile("s_waitcnt vmcnt(10)" ::: "memory");
    __builtin_amdgcn_s_barrier();
    const char* Kb = KB2 + (t & 1) * 16384;
    const char* Vb = VB2 + (t & 1) * 16384;

    // QK: rows [wm*32,+32) x cols [wn*16,+16)
    f32x4 acc[2] = {};
    __builtin_amdgcn_s_setprio(1);
#pragma unroll
    for (int ks = 0; ks < 8; ++ks) {
      bf16x8 kb = *(const bf16x8*)(Kb + krow * 512 + ((ks * 64 + lhi * 16) ^ ((krow & 7) << 4)));
      acc[0] = mfma16(qf[0][ks], kb, acc[0]);
      acc[1] = mfma16(qf[1][ks], kb, acc[1]);
    }
    __builtin_amdgcn_s_setprio(0);

    // exp/normalize/mask -> Psh (bf16, swz ((rr>>2)&3)<<4)
#pragma unroll
    for (int m = 0; m < 2; ++m)
#pragma unroll
      for (int j = 0; j < 4; ++j) {
        int rr = wm * 32 + m * 16 + lhi * 4 + j;
        int qr = qbase + rr;
        int kc = t * 32 + krow;
        float e = (kc <= qr) ? __expf(acc[m][j] * 0.0625f) * inv4[m][j] : 0.f;
        int addr = rr * 64 + krow * 2;
        *(bf16_t*)(Psh + (addr ^ (((rr >> 2) & 3) << 4))) = (bf16_t)e;
      }
    asm volatile("s_waitcnt lgkmcnt(0)" ::: "memory");   // P writes visible
    __builtin_amdgcn_s_barrier();

    // dump Psh -> pout as f32 (coalesced f32x4); 2 stores, never drained in-loop
    {
      int row = tid >> 2;
      int ch  = (tid & 3) * 16;
      bf16x8 p8 = *(const bf16x8*)(Psh + row * 64 + (ch ^ (((row >> 2) & 3) << 4)));
      float* dst = pout + ((size_t)bh * 2048 + qbase + row) * 2048 + t * 32 + (tid & 3) * 8;
      f32x4 lo = { (float)p8[0], (float)p8[1], (float)p8[2], (float)p8[3] };
      f32x4 hi = { (float)p8[4], (float)p8[5], (float)p8[6], (float)p8[7] };
      *(f32x4*)dst = lo;
      *(f32x4*)(dst + 4) = hi;
    }

    // PV: all 64 P rows x this wave's d-cols [w*64,+64)
    bf16x8 pa[4], vb[4];
#pragma unroll
    for (int m4 = 0; m4 < 4; ++m4) {
      int pr = m4 * 16 + l15;
      pa[m4] = *(const bf16x8*)(Psh + ((pr * 64 + lhi * 16) ^ (((pr >> 2) & 3) << 4)));
    }
#pragma unroll
    for (int n = 0; n < 4; ++n) {
      int vr = w * 64 + n * 16 + l15;
      vb[n] = *(const bf16x8*)(Vb + ((vr * 64 + lhi * 16) ^ (((vr >> 2) & 3) << 4)));
    }
    __builtin_amdgcn_s_setprio(1);
#pragma unroll
    for (int m4 = 0; m4 < 4; ++m4)
#pragma unroll
      for (int n = 0; n < 4; ++n)
        ctx[m4][n] = mfma16(pa[m4], vb[n], ctx[m4][n]);
    __builtin_amdgcn_s_setprio(0);

    asm volatile("s_waitcnt lgkmcnt(0)" ::: "memory");   // Psh/Vsh reads drained
    __builtin_amdgcn_s_barrier();
    if (t + 2 < nktB) PSTAGE(t + 2);                      // 2-deep prefetch
  }
#undef PSTAGE

  // ctx write: (b, s, h*256 + d) bf16
  int b = bh >> 3, h = bh & 7;
#pragma unroll
  for (int m4 = 0; m4 < 4; ++m4)
#pragma unroll
    for (int n = 0; n < 4; ++n)
#pragma unroll
      for (int j = 0; j < 4; ++j) {
        int qr = qbase + m4 * 16 + lhi * 4 + j;
        ctxo[((size_t)b * 2048 + qr) * 2048 + h * 256 + w * 64 + n * 16 + l15] = (bf16_t)ctx[m4][n][j];
      }

  // zero-fill masked region beyond causal boundary
  int zs = qbase + 64;
  for (int r = 0; r < 64; ++r) {
    size_t base2 = ((size_t)bh * 2048 + qbase + r) * 2048;
    for (int c = zs + tid * 4; c < 2048; c += 1024)
      *(float4*)(pout + base2 + c) = make_float4(0.f, 0.f, 0.f, 0.f);
  }
}

// ---------------- host launch ----------------
extern "C" void kernel_launch(void* const* d_in, const int* in_sizes, int n_in,
                              void* d_out, int out_size, void* d_ws, size_t ws_size,
                              hipStream_t stream) {
  const float* x     = (const float*)d_in[0];
  const float* ln1g  = (const float*)d_in[2];
  const float* ln1b  = (const float*)d_in[3];
  const float* wq_w  = (const float*)d_in[4];
  const float* wq_b  = (const float*)d_in[5];
  const float* wk_w  = (const float*)d_in[6];
  const float* wk_b  = (const float*)d_in[7];
  const float* wv_w  = (const float*)d_in[8];
  const float* wv_b  = (const float*)d_in[9];
  const float* dw    = (const float*)d_in[10];
  const float* db    = (const float*)d_in[11];
  const float* ln2g  = (const float*)d_in[12];
  const float* ln2b  = (const float*)d_in[13];
  const float* f1w   = (const float*)d_in[14];
  const float* f1b   = (const float*)d_in[15];
  const float* f2w   = (const float*)d_in[16];
  const float* f2b   = (const float*)d_in[17];

  char* ws = (char*)d_ws;
  const size_t MB = 1u << 20;
  float*  xn_f = (float*) (ws + 0 * MB);
  bf16_t* xn_b = (bf16_t*)(ws + 4 * MB);
  bf16_t* q_b  = (bf16_t*)(ws + 6 * MB);
  bf16_t* k_b  = (bf16_t*)(ws + 22 * MB);
  bf16_t* ctx_b= (bf16_t*)(ws + 38 * MB);
  bf16_t* vt_b = (bf16_t*)(ws + 54 * MB);
  float*  x1_f = (float*) (ws + 70 * MB);
  bf16_t* m_b  = (bf16_t*)(ws + 74 * MB);
  bf16_t* h_b  = (bf16_t*)(ws + 76 * MB);
  bf16_t* wq_bf = (bf16_t*)(ws + 84 * MB);
  bf16_t* wk_bf = wq_bf + 524288;
  bf16_t* wv_bf = wk_bf + 524288;
  bf16_t* dw_bf = wv_bf + 524288;
  bf16_t* f1_bf = dw_bf + 524288;
  bf16_t* f2_bf = f1_bf + 262144;
  float* parts_d = (float*)q_b;
  float* parts_f = (float*)k_b;

  float* out0 = (float*)d_out;
  float* pout = out0 + 1048576;

  k1_lncvt<<<3584, 256, 0, stream>>>(x, ln1g, ln1b, xn_f, xn_b,
                                     wq_w, wk_w, wv_w, dw, f1w, f2w,
                                     wq_bf, wk_bf, wv_bf, dw_bf, f1_bf, f2_bf);

  gemm_qkv<<<dim3(48, 32), 256, 0, stream>>>(xn_b, wq_bf, wk_bf, wv_bf,
                                             wq_b, wk_b, wv_b, q_b, k_b, vt_b);

  attn_fused2<<<512, 256, 0, stream>>>(q_b, k_b, vt_b, pout, ctx_b);

  gemm_part<<<dim3(2, 32, 4), 256, 0, stream>>>(ctx_b, dw_bf, 2048, 512, parts_d);
  reduce_ln<<<1024, 256, 0, stream>>>(parts_d, db, xn_f, ln2g, ln2b, x1_f, m_b);

  gemm_fc1<<<dim3(8, 32), 256, 0, stream>>>(m_b, f1_bf, f1b, h_b);

  gemm_part<<<dim3(2, 32, 4), 256, 0, stream>>>(h_b, f2_bf, 1024, 256, parts_f);
  reduce4<<<1024, 256, 0, stream>>>(parts_f, f2b, x1_f, out0);
}

// Round 14
// 200.759 us; speedup vs baseline: 1.5854x; 1.0039x over previous
//
#include <hip/hip_runtime.h>
#include <hip/hip_bf16.h>

// TransformerLayer on MI355X (gfx950). Round 14 = R13 + V de-staging:
//  - V stored TILED by gemm_qkv epilogue: vt[bh][kt][256 d][32 s] (16KB tiles)
//    -> pass B loads vb direct global->reg, perfectly coalesced (1KB dense per
//    wave-instruction), L2-resident. R7/R10's direct-V failure was the STRIDED
//    layout, not the staging removal.
//  - attn pass B: V LDS staging removed (saves ~32KB LDS traffic + 4 vmem
//    per tile); vb via inline-asm global_load_dwordx4 + counted vmcnt
//    (top w(10) retires PSTAGE(t) [2-deep]; PV w(6) retires vb(t); last-iter
//    w(6)/w(2)); sched_barrier(0) after PV wait (rule: asm wait + reg-only
//    MFMA needs the fence).
//  - LDS 70.4 -> 66.3 KB. Pass A + GEMM stack byte-identical to R13.

typedef __bf16 bf16_t;
typedef __bf16 bf16x8 __attribute__((ext_vector_type(8)));
typedef __bf16 bf16x4 __attribute__((ext_vector_type(4)));
typedef float  f32x4  __attribute__((ext_vector_type(4)));

#define DEV __device__ __forceinline__

DEV f32x4 mfma16(bf16x8 a, bf16x8 b, f32x4 c) {
  return __builtin_amdgcn_mfma_f32_16x16x32_bf16(a, b, c, 0, 0, 0);
}

DEV void gload16(const void* g, void* l) {
  __builtin_amdgcn_global_load_lds(
      (const __attribute__((address_space(1))) unsigned int*)g,
      (__attribute__((address_space(3))) unsigned int*)l, 16, 0, 0);
}

// ---------------- fused LN1 + weight cvt (grid 1024 + 2560) ----------------
__global__ __launch_bounds__(256) void k1_lncvt(
    const float* __restrict__ x, const float* __restrict__ g, const float* __restrict__ bta,
    float* __restrict__ of, bf16_t* __restrict__ ob,
    const float* __restrict__ s0, const float* __restrict__ s1,
    const float* __restrict__ s2, const float* __restrict__ s3,
    const float* __restrict__ s4, const float* __restrict__ s5,
    bf16_t* __restrict__ d0, bf16_t* __restrict__ d1, bf16_t* __restrict__ d2,
    bf16_t* __restrict__ d3, bf16_t* __restrict__ d4, bf16_t* __restrict__ d5) {
  int bid = blockIdx.x;
  if (bid < 1024) {
    int row = bid * 4 + (threadIdx.x >> 6);
    int l = threadIdx.x & 63;
    const float4 v = *(const float4*)(x + (size_t)row * 256 + l * 4);
    float s  = v.x + v.y + v.z + v.w;
    float s2 = v.x*v.x + v.y*v.y + v.z*v.z + v.w*v.w;
#pragma unroll
    for (int o = 1; o < 64; o <<= 1) { s += __shfl_xor(s, o, 64); s2 += __shfl_xor(s2, o, 64); }
    float m   = s * (1.f/256.f);
    float var = s2 * (1.f/256.f) - m * m;
    float rs  = rsqrtf(var + 1e-9f);
    const float4 gv = *(const float4*)(g   + l * 4);
    const float4 bv = *(const float4*)(bta + l * 4);
    float4 y;
    y.x = (v.x - m) * rs * gv.x + bv.x;
    y.y = (v.y - m) * rs * gv.y + bv.y;
    y.z = (v.z - m) * rs * gv.z + bv.z;
    y.w = (v.w - m) * rs * gv.w + bv.w;
    *(float4*)(of + (size_t)row * 256 + l * 4) = y;
    bf16x4 yb = { (bf16_t)y.x, (bf16_t)y.y, (bf16_t)y.z, (bf16_t)y.w };
    *(bf16x4*)(ob + (size_t)row * 256 + l * 4) = yb;
  } else {
    int i = (bid - 1024) * 256 + threadIdx.x;
    const float* s; bf16_t* d; int off;
    if      (i < 131072) { s = s0; d = d0; off = i; }
    else if (i < 262144) { s = s1; d = d1; off = i - 131072; }
    else if (i < 393216) { s = s2; d = d2; off = i - 262144; }
    else if (i < 524288) { s = s3; d = d3; off = i - 393216; }
    else if (i < 589824) { s = s4; d = d4; off = i - 524288; }
    else                 { s = s5; d = d5; off = i - 589824; }
    float4 v = ((const float4*)s)[off];
    bf16x4 o = { (bf16_t)v.x, (bf16_t)v.y, (bf16_t)v.z, (bf16_t)v.w };
    ((bf16x4*)d)[off] = o;
  }
}

// ---------------- 2-phase double-buffered 128x128 GEMM core ----------------
DEV void gemm_core(const bf16_t* __restrict__ A, const bf16_t* __restrict__ W,
                   int lda, int row0, int col0, int k0, int kiters,
                   char* Asb, char* Bsb, f32x4 (&acc)[4][4]) {
  int tid = threadIdx.x, w = tid >> 6, l = tid & 63, l15 = l & 15, lhi = l >> 4;
  int wr = (w >> 1) * 64, wc = (w & 1) * 64;

#define STAGE(buf, kk) do {                                                   \
    char* Ad = Asb + (buf) * 8192 + w * 1024;                                 \
    char* Bd = Bsb + (buf) * 8192 + w * 1024;                                 \
    _Pragma("unroll")                                                         \
    for (int j = 0; j < 2; ++j) {                                             \
      int idx = (j * 256 + tid) * 8; int r = idx >> 5, c = idx & 31;          \
      gload16(A + (size_t)(row0 + r) * lda + (kk) + c, Ad + j * 4096);        \
      gload16(W + (size_t)(col0 + r) * lda + (kk) + c, Bd + j * 4096);        \
    } } while (0)

  STAGE(0, k0);
  for (int t = 0; t < kiters; ++t) {
    int cur = t & 1;
    if (t + 1 < kiters) {
      STAGE(cur ^ 1, k0 + (t + 1) * 32);
      asm volatile("s_waitcnt vmcnt(4)" ::: "memory");
    } else {
      asm volatile("s_waitcnt vmcnt(0)" ::: "memory");
    }
    __builtin_amdgcn_s_barrier();
    asm volatile("" ::: "memory");
    const bf16_t* As = (const bf16_t*)(Asb + cur * 8192);
    const bf16_t* Bs = (const bf16_t*)(Bsb + cur * 8192);
    bf16x8 af[4], bfr[4];
#pragma unroll
    for (int m = 0; m < 4; ++m)
      af[m] = *(const bf16x8*)(As + (wr + 16 * m + l15) * 32 + lhi * 8);
#pragma unroll
    for (int n = 0; n < 4; ++n)
      bfr[n] = *(const bf16x8*)(Bs + (wc + 16 * n + l15) * 32 + lhi * 8);
#pragma unroll
    for (int m = 0; m < 4; ++m)
#pragma unroll
      for (int n = 0; n < 4; ++n)
        acc[m][n] = mfma16(af[m], bfr[n], acc[m][n]);
    asm volatile("s_waitcnt lgkmcnt(0)" ::: "memory");
    __builtin_amdgcn_s_barrier();
  }
#undef STAGE
}

// ---------------- fused QKV: grid (48, 32); V written TILED ----------------
// vt layout: [bh][kt=s/32][256 d][32 s] bf16 (16KB per tile)
__global__ __launch_bounds__(256, 4) void gemm_qkv(
    const bf16_t* __restrict__ A,
    const bf16_t* __restrict__ W0, const bf16_t* __restrict__ W1, const bf16_t* __restrict__ W2,
    const float* __restrict__ b0, const float* __restrict__ b1, const float* __restrict__ b2,
    bf16_t* __restrict__ qo, bf16_t* __restrict__ ko, bf16_t* __restrict__ vto) {
  __shared__ char smem[34816];   // staging 32KB | V-transpose 128x136 bf16
  char* Asb = smem;
  char* Bsb = smem + 16384;
  int bx = blockIdx.x;
  int wsel = bx >> 4, cb = bx & 15;
  const bf16_t* W    = wsel == 0 ? W0 : (wsel == 1 ? W1 : W2);
  const float*  bias = wsel == 0 ? b0 : (wsel == 1 ? b1 : b2);
  int row0 = blockIdx.y * 128, col0 = cb * 128;
  f32x4 acc[4][4] = {};
  gemm_core(A, W, 256, row0, col0, 0, 8, Asb, Bsb, acc);

  int tid = threadIdx.x, w = tid >> 6, l = tid & 63, l15 = l & 15, lhi = l >> 4;
  int wr = (w >> 1) * 64, wc = (w & 1) * 64;

  if (wsel < 2) {
    bf16_t* out = wsel == 0 ? qo : ko;
#pragma unroll
    for (int m = 0; m < 4; ++m)
#pragma unroll
      for (int n = 0; n < 4; ++n)
#pragma unroll
        for (int j = 0; j < 4; ++j) {
          int row = row0 + wr + 16 * m + lhi * 4 + j;
          int col = col0 + wc + 16 * n + l15;
          float v = acc[m][n][j] + bias[col];
          out[((size_t)((row >> 11) * 8 + (col >> 8)) * 2048 + (row & 2047)) * 256 + (col & 255)] = (bf16_t)v;
        }
  } else {
    // V: transpose in LDS, write TILED V^T: vt[bh][kt][d][32]
    __syncthreads();   // full drain before overwriting staging LDS
    bf16_t* T = (bf16_t*)smem;   // [128 d][136 stride] bf16
#pragma unroll
    for (int m = 0; m < 4; ++m)
#pragma unroll
      for (int n = 0; n < 4; ++n) {
        int d = wc + 16 * n + l15;
        int s = wr + 16 * m + lhi * 4;
        bf16x4 v4;
#pragma unroll
        for (int j = 0; j < 4; ++j) v4[j] = (bf16_t)(acc[m][n][j] + bias[col0 + d]);
        *(bf16x4*)(T + d * 136 + s) = v4;
      }
    __syncthreads();
    int bh = ((row0 >> 11) << 3) + (col0 >> 8);
    int d0 = col0 & 255, s0g = row0 & 2047;
#pragma unroll
    for (int p = 0; p < 8; ++p) {
      int idx = p * 256 + tid;
      int d = idx >> 4, c = (idx & 15) * 8;
      bf16x8 v8 = *(const bf16x8*)(T + d * 136 + c);
      int kt = (s0g + c) >> 5, so = c & 31;
      *(bf16x8*)(vto + (((size_t)bh * 64 + kt) * 256 + d0 + d) * 32 + so) = v8;
    }
  }
}

// ---------------- split-K partial GEMM: N=256, grid (2, 32, 4) ----------------
__global__ __launch_bounds__(256, 4) void gemm_part(
    const bf16_t* __restrict__ A, const bf16_t* __restrict__ W,
    int lda, int ksub, float* __restrict__ parts) {
  __shared__ char Asb[2 * 8192];
  __shared__ char Bsb[2 * 8192];
  int z = blockIdx.z;
  int row0 = blockIdx.y * 128, col0 = blockIdx.x * 128;
  f32x4 acc[4][4] = {};
  gemm_core(A, W, lda, row0, col0, z * ksub, ksub >> 5, Asb, Bsb, acc);

  int tid = threadIdx.x, w = tid >> 6, l = tid & 63, l15 = l & 15, lhi = l >> 4;
  int wr = (w >> 1) * 64, wc = (w & 1) * 64;
  float* p = parts + (size_t)z * 1048576;
#pragma unroll
  for (int m = 0; m < 4; ++m)
#pragma unroll
    for (int n = 0; n < 4; ++n)
#pragma unroll
      for (int j = 0; j < 4; ++j) {
        int row = row0 + wr + 16 * m + lhi * 4 + j;
        int col = col0 + wc + 16 * n + l15;
        p[(size_t)row * 256 + col] = acc[m][n][j];
      }
}

// ---------------- reduce 4 partials + bias + residual (final out) ----------------
__global__ __launch_bounds__(256) void reduce4(
    const float* __restrict__ parts, const float* __restrict__ bias,
    const float* __restrict__ res, float* __restrict__ out) {
  int i = blockIdx.x * 256 + threadIdx.x;
  f32x4 s = *(const f32x4*)(parts + (size_t)i * 4);
  s += *(const f32x4*)(parts + 1048576 + (size_t)i * 4);
  s += *(const f32x4*)(parts + 2097152 + (size_t)i * 4);
  s += *(const f32x4*)(parts + 3145728 + (size_t)i * 4);
  s += *(const f32x4*)(res + (size_t)i * 4);
  s += *(const f32x4*)(bias + (i & 63) * 4);
  *(f32x4*)(out + (size_t)i * 4) = s;
}

// ---------------- fused dense-reduce + residual + LN2 ----------------
__global__ __launch_bounds__(256) void reduce_ln(
    const float* __restrict__ parts, const float* __restrict__ bias,
    const float* __restrict__ res, const float* __restrict__ g,
    const float* __restrict__ bta, float* __restrict__ x1o, bf16_t* __restrict__ mo) {
  int row = blockIdx.x * 4 + (threadIdx.x >> 6);
  int l = threadIdx.x & 63;
  size_t base = (size_t)row * 256 + l * 4;
  f32x4 s = *(const f32x4*)(parts + base);
  s += *(const f32x4*)(parts + 1048576 + base);
  s += *(const f32x4*)(parts + 2097152 + base);
  s += *(const f32x4*)(parts + 3145728 + base);
  s += *(const f32x4*)(res + base);
  s += *(const f32x4*)(bias + l * 4);
  *(f32x4*)(x1o + base) = s;
  float sm = s[0] + s[1] + s[2] + s[3];
  float s2 = s[0]*s[0] + s[1]*s[1] + s[2]*s[2] + s[3]*s[3];
#pragma unroll
  for (int o = 1; o < 64; o <<= 1) { sm += __shfl_xor(sm, o, 64); s2 += __shfl_xor(s2, o, 64); }
  float m   = sm * (1.f/256.f);
  float var = s2 * (1.f/256.f) - m * m;
  float rs  = rsqrtf(var + 1e-9f);
  const float4 gv = *(const float4*)(g   + l * 4);
  const float4 bv = *(const float4*)(bta + l * 4);
  bf16x4 yb;
  yb[0] = (bf16_t)((s[0] - m) * rs * gv.x + bv.x);
  yb[1] = (bf16_t)((s[1] - m) * rs * gv.y + bv.y);
  yb[2] = (bf16_t)((s[2] - m) * rs * gv.z + bv.z);
  yb[3] = (bf16_t)((s[3] - m) * rs * gv.w + bv.w);
  *(bf16x4*)(mo + base) = yb;
}

// ---------------- FC1 with gelu ----------------
__global__ __launch_bounds__(256, 4) void gemm_fc1(
    const bf16_t* __restrict__ A, const bf16_t* __restrict__ W,
    const float* __restrict__ bias, bf16_t* __restrict__ out) {
  __shared__ char Asb[2 * 8192];
  __shared__ char Bsb[2 * 8192];
  int row0 = blockIdx.y * 128, col0 = blockIdx.x * 128;
  f32x4 acc[4][4] = {};
  gemm_core(A, W, 256, row0, col0, 0, 8, Asb, Bsb, acc);

  int tid = threadIdx.x, w = tid >> 6, l = tid & 63, l15 = l & 15, lhi = l >> 4;
  int wr = (w >> 1) * 64, wc = (w & 1) * 64;
#pragma unroll
  for (int m = 0; m < 4; ++m)
#pragma unroll
    for (int n = 0; n < 4; ++n)
#pragma unroll
      for (int j = 0; j < 4; ++j) {
        int row = row0 + wr + 16 * m + lhi * 4 + j;
        int col = col0 + wc + 16 * n + l15;
        float t = acc[m][n][j] + bias[col];
        float ge = 0.5f * t * (1.f + tanhf(0.7978845608f * t * (1.f + 0.044715f * t * t)));
        out[(size_t)row * 1024 + col] = (bf16_t)ge;
      }
}

// ---------------- attn_fused2: pass A rowsum (TK=64) + pass B P/PV (TK=32) --
// grid 512: bh = bx&15; bx<256: qt=31-(bx>>4) (big first); else qt=(bx-256)>>4.
__global__ __launch_bounds__(256, 2) void attn_fused2(
    const bf16_t* __restrict__ qg, const bf16_t* __restrict__ kg,
    const bf16_t* __restrict__ vt, float* __restrict__ pout,
    bf16_t* __restrict__ ctxo) {
  __shared__ __align__(16) char smem[66304];
  // pass A: KA dbuf 2x32KB = smem[0..65536)
  // pass B: KB2 dbuf 2x16KB = smem[0..32768), Psh 4KB @32768 (inside old KA buf1)
  // sl 512B @65536, invsh 256B @66048
  char*  KA    = smem;
  char*  KB2   = smem;
  char*  Psh   = smem + 32768;
  float* sl    = (float*)(smem + 65536);
  float* invsh = (float*)(smem + 66048);

  int bx = blockIdx.x;
  int bh = bx & 15;
  int qt = (bx < 256) ? (31 - (bx >> 4)) : ((bx - 256) >> 4);
  int qbase = qt * 64;

  int tid = threadIdx.x, w = tid >> 6, l = tid & 63;
  int l15 = l & 15, lhi = l >> 4;
  int wm = w >> 1, wn = w & 1;
  const bf16_t* Q  = qg + (size_t)bh * 2048 * 256;
  const bf16_t* K  = kg + (size_t)bh * 2048 * 256;
  const bf16_t* Vt = vt + (size_t)bh * 524288;   // tiled: [kt][256 d][32 s]

  // Q fragments (both passes): rows qbase + wm*32 + m*16 + l15
  bf16x8 qf[2][8];
#pragma unroll
  for (int m = 0; m < 2; ++m)
#pragma unroll
    for (int ks = 0; ks < 8; ++ks)
      qf[m][ks] = *(const bf16x8*)(Q + (size_t)(qbase + wm * 32 + m * 16 + l15) * 256 + ks * 32 + lhi * 8);

  // ================= pass A: masked exp rowsums =================
  int nktA = qt + 1;
#define RSTAGE(t_) do {                                                        \
    char* dst = KA + ((t_) & 1) * 32768 + w * 1024;                            \
    _Pragma("unroll")                                                          \
    for (int j = 0; j < 8; ++j) {                                              \
      int idx = (j * 256 + tid) * 16; int r = idx >> 9;                        \
      int co = (idx & 511) ^ ((r & 7) << 4);                                   \
      gload16(K + (size_t)((t_) * 64 + r) * 256 + (co >> 1), dst + j * 4096);  \
    } } while (0)

  RSTAGE(0);
  if (nktA > 1) RSTAGE(1);

  float sums[2][4] = {};
  for (int t = 0; t < nktA; ++t) {
    if (t + 1 < nktA) asm volatile("s_waitcnt vmcnt(8)" ::: "memory");
    else              asm volatile("s_waitcnt vmcnt(0)" ::: "memory");
    __builtin_amdgcn_s_barrier();
    const char* Kb = KA + (t & 1) * 32768;
    f32x4 acc[2][2] = {};
    __builtin_amdgcn_s_setprio(1);
#pragma unroll
    for (int ks = 0; ks < 8; ++ks) {
#pragma unroll
      for (int n2 = 0; n2 < 2; ++n2) {
        int row = wn * 32 + n2 * 16 + l15;
        bf16x8 kb = *(const bf16x8*)(Kb + row * 512 + ((ks * 64 + lhi * 16) ^ ((row & 7) << 4)));
#pragma unroll
        for (int m = 0; m < 2; ++m)
          acc[m][n2] = mfma16(qf[m][ks], kb, acc[m][n2]);
      }
    }
    __builtin_amdgcn_s_setprio(0);
#pragma unroll
    for (int m = 0; m < 2; ++m)
#pragma unroll
      for (int n2 = 0; n2 < 2; ++n2)
#pragma unroll
        for (int j = 0; j < 4; ++j) {
          int qr = qbase + wm * 32 + m * 16 + lhi * 4 + j;
          int kc = t * 64 + wn * 32 + n2 * 16 + l15;
          sums[m][j] += (kc <= qr) ? __expf(acc[m][n2][j] * 0.0625f) : 0.f;
        }
    asm volatile("s_waitcnt lgkmcnt(0)" ::: "memory");
    __builtin_amdgcn_s_barrier();
    if (t + 2 < nktA) RSTAGE(t + 2);
  }
#undef RSTAGE

  // ---- pass B staging macro (K only, 4 loads) ----
#define PSTAGE(t_) do {                                                         \
    char* kd = KB2 + ((t_) & 1) * 16384 + w * 1024;                             \
    _Pragma("unroll")                                                           \
    for (int j = 0; j < 4; ++j) {                                               \
      int idx = (j * 256 + tid) * 16;                                           \
      int r = idx >> 9; int co = (idx & 511) ^ ((r & 7) << 4);                  \
      gload16(K + (size_t)((t_) * 32 + r) * 256 + (co >> 1), kd + j * 4096);    \
    } } while (0)

  // hoisted pass-B prefetch (K tiles 0,1) + first V tile; the reduction's
  // __syncthreads() drains vmcnt, so these complete under the reduction.
  PSTAGE(0);
  PSTAGE(1);
  bf16x8 vb[4];
#pragma unroll
  for (int n4 = 0; n4 < 4; ++n4) {
    const bf16_t* vp = Vt + ((size_t)0 * 256 + (w * 64 + n4 * 16 + l15)) * 32 + lhi * 8;
    asm volatile("global_load_dwordx4 %0, %1, off" : "=v"(vb[n4]) : "v"(vp) : "memory");
  }

#pragma unroll
  for (int m = 0; m < 2; ++m)
#pragma unroll
    for (int j = 0; j < 4; ++j)
#pragma unroll
      for (int o = 1; o < 16; o <<= 1)
        sums[m][j] += __shfl_xor(sums[m][j], o, 64);
  if (l15 == 0)
#pragma unroll
    for (int m = 0; m < 2; ++m)
#pragma unroll
      for (int j = 0; j < 4; ++j)
        sl[wn * 64 + wm * 32 + m * 16 + lhi * 4 + j] = sums[m][j];
  __syncthreads();
  if (tid < 64) invsh[tid] = 1.f / (sl[tid] + sl[64 + tid]);
  __syncthreads();
  float inv4[2][4];
#pragma unroll
  for (int m = 0; m < 2; ++m)
#pragma unroll
    for (int j = 0; j < 4; ++j)
      inv4[m][j] = invsh[wm * 32 + m * 16 + lhi * 4 + j];
  __syncthreads();   // all invsh reads done; drains vmcnt (prologue complete)

  // ================= pass B: P-write + PV, TK=32 =============
  // Queue ledger per steady iter t (oldest->newest at top):
  //   P(t)[4], d(t-1)[2], v(t)[4], P(t+1)[4]  = 14
  //   top w(10) retires P(t) (2-deep prefetch);  +d(t) -> 12;
  //   PV w(6) retires d(t-1)+v(t), leaves P(t+1)+d(t);  +v(t+1), +P(t+2).
  // Tail: t==last: top w(6) retires P(t); PV w(2) retires v(t).
  int nktB = 2 * (qt + 1);
  int krow = wn * 16 + l15;
  f32x4 ctx[4][4] = {};
  for (int t = 0; t < nktB; ++t) {
    if (t == 0)             asm volatile("s_waitcnt vmcnt(8)"  ::: "memory");
    else if (t + 1 == nktB) asm volatile("s_waitcnt vmcnt(6)"  ::: "memory");
    else                    asm volatile("s_waitcnt vmcnt(10)" ::: "memory");
    __builtin_amdgcn_s_barrier();
    const char* Kb = KB2 + (t & 1) * 16384;

    // QK: rows [wm*32,+32) x cols [wn*16,+16)
    f32x4 acc[2] = {};
    __builtin_amdgcn_s_setprio(1);
#pragma unroll
    for (int ks = 0; ks < 8; ++ks) {
      bf16x8 kb = *(const bf16x8*)(Kb + krow * 512 + ((ks * 64 + lhi * 16) ^ ((krow & 7) << 4)));
      acc[0] = mfma16(qf[0][ks], kb, acc[0]);
      acc[1] = mfma16(qf[1][ks], kb, acc[1]);
    }
    __builtin_amdgcn_s_setprio(0);

    // exp/normalize/mask -> Psh (bf16, swz ((rr>>2)&3)<<4)
#pragma unroll
    for (int m = 0; m < 2; ++m)
#pragma unroll
      for (int j = 0; j < 4; ++j) {
        int rr = wm * 32 + m * 16 + lhi * 4 + j;
        int qr = qbase + rr;
        int kc = t * 32 + krow;
        float e = (kc <= qr) ? __expf(acc[m][j] * 0.0625f) * inv4[m][j] : 0.f;
        int addr = rr * 64 + krow * 2;
        *(bf16_t*)(Psh + (addr ^ (((rr >> 2) & 3) << 4))) = (bf16_t)e;
      }
    asm volatile("s_waitcnt lgkmcnt(0)" ::: "memory");   // P writes visible
    __builtin_amdgcn_s_barrier();

    // dump Psh -> pout as f32 (coalesced f32x4); 2 stores, retired next iter's PV-wait
    {
      int row = tid >> 2;
      int ch  = (tid & 3) * 16;
      bf16x8 p8 = *(const bf16x8*)(Psh + row * 64 + (ch ^ (((row >> 2) & 3) << 4)));
      float* dst = pout + ((size_t)bh * 2048 + qbase + row) * 2048 + t * 32 + (tid & 3) * 8;
      f32x4 lo = { (float)p8[0], (float)p8[1], (float)p8[2], (float)p8[3] };
      f32x4 hi = { (float)p8[4], (float)p8[5], (float)p8[6], (float)p8[7] };
      *(f32x4*)dst = lo;
      *(f32x4*)(dst + 4) = hi;
    }

    // PV: wait for vb(t), then MFMA with P rows from LDS
    if (t + 1 == nktB) asm volatile("s_waitcnt vmcnt(2)" ::: "memory");
    else               asm volatile("s_waitcnt vmcnt(6)" ::: "memory");
    __builtin_amdgcn_sched_barrier(0);
    bf16x8 pa[4];
#pragma unroll
    for (int m4 = 0; m4 < 4; ++m4) {
      int pr = m4 * 16 + l15;
      pa[m4] = *(const bf16x8*)(Psh + ((pr * 64 + lhi * 16) ^ (((pr >> 2) & 3) << 4)));
    }
    __builtin_amdgcn_s_setprio(1);
#pragma unroll
    for (int m4 = 0; m4 < 4; ++m4)
#pragma unroll
      for (int n = 0; n < 4; ++n)
        ctx[m4][n] = mfma16(pa[m4], vb[n], ctx[m4][n]);
    __builtin_amdgcn_s_setprio(0);

    asm volatile("s_waitcnt lgkmcnt(0)" ::: "memory");   // Psh/Ksh reads drained
    __builtin_amdgcn_s_barrier();
    // issue vb(t+1) then PSTAGE(t+2): keeps queue order [.., v(t+1), P(t+2)]
    if (t + 1 < nktB) {
#pragma unroll
      for (int n4 = 0; n4 < 4; ++n4) {
        const bf16_t* vp = Vt + ((size_t)(t + 1) * 256 + (w * 64 + n4 * 16 + l15)) * 32 + lhi * 8;
        asm volatile("global_load_dwordx4 %0, %1, off" : "=v"(vb[n4]) : "v"(vp) : "memory");
      }
    }
    if (t + 2 < nktB) PSTAGE(t + 2);
  }
#undef PSTAGE

  // ctx write: (b, s, h*256 + d) bf16
  int b = bh >> 3, h = bh & 7;
#pragma unroll
  for (int m4 = 0; m4 < 4; ++m4)
#pragma unroll
    for (int n = 0; n < 4; ++n)
#pragma unroll
      for (int j = 0; j < 4; ++j) {
        int qr = qbase + m4 * 16 + lhi * 4 + j;
        ctxo[((size_t)b * 2048 + qr) * 2048 + h * 256 + w * 64 + n * 16 + l15] = (bf16_t)ctx[m4][n][j];
      }

  // zero-fill masked region beyond causal boundary
  int zs = qbase + 64;
  for (int r = 0; r < 64; ++r) {
    size_t base2 = ((size_t)bh * 2048 + qbase + r) * 2048;
    for (int c = zs + tid * 4; c < 2048; c += 1024)
      *(float4*)(pout + base2 + c) = make_float4(0.f, 0.f, 0.f, 0.f);
  }
}

// ---------------- host launch ----------------
extern "C" void kernel_launch(void* const* d_in, const int* in_sizes, int n_in,
                              void* d_out, int out_size, void* d_ws, size_t ws_size,
                              hipStream_t stream) {
  const float* x     = (const float*)d_in[0];
  const float* ln1g  = (const float*)d_in[2];
  const float* ln1b  = (const float*)d_in[3];
  const float* wq_w  = (const float*)d_in[4];
  const float* wq_b  = (const float*)d_in[5];
  const float* wk_w  = (const float*)d_in[6];
  const float* wk_b  = (const float*)d_in[7];
  const float* wv_w  = (const float*)d_in[8];
  const float* wv_b  = (const float*)d_in[9];
  const float* dw    = (const float*)d_in[10];
  const float* db    = (const float*)d_in[11];
  const float* ln2g  = (const float*)d_in[12];
  const float* ln2b  = (const float*)d_in[13];
  const float* f1w   = (const float*)d_in[14];
  const float* f1b   = (const float*)d_in[15];
  const float* f2w   = (const float*)d_in[16];
  const float* f2b   = (const float*)d_in[17];

  char* ws = (char*)d_ws;
  const size_t MB = 1u << 20;
  float*  xn_f = (float*) (ws + 0 * MB);
  bf16_t* xn_b = (bf16_t*)(ws + 4 * MB);
  bf16_t* q_b  = (bf16_t*)(ws + 6 * MB);
  bf16_t* k_b  = (bf16_t*)(ws + 22 * MB);
  bf16_t* ctx_b= (bf16_t*)(ws + 38 * MB);
  bf16_t* vt_b = (bf16_t*)(ws + 54 * MB);
  float*  x1_f = (float*) (ws + 70 * MB);
  bf16_t* m_b  = (bf16_t*)(ws + 74 * MB);
  bf16_t* h_b  = (bf16_t*)(ws + 76 * MB);
  bf16_t* wq_bf = (bf16_t*)(ws + 84 * MB);
  bf16_t* wk_bf = wq_bf + 524288;
  bf16_t* wv_bf = wk_bf + 524288;
  bf16_t* dw_bf = wv_bf + 524288;
  bf16_t* f1_bf = dw_bf + 524288;
  bf16_t* f2_bf = f1_bf + 262144;
  float* parts_d = (float*)q_b;
  float* parts_f = (float*)k_b;

  float* out0 = (float*)d_out;
  float* pout = out0 + 1048576;

  k1_lncvt<<<3584, 256, 0, stream>>>(x, ln1g, ln1b, xn_f, xn_b,
                                     wq_w, wk_w, wv_w, dw, f1w, f2w,
                                     wq_bf, wk_bf, wv_bf, dw_bf, f1_bf, f2_bf);

  gemm_qkv<<<dim3(48, 32), 256, 0, stream>>>(xn_b, wq_bf, wk_bf, wv_bf,
                                             wq_b, wk_b, wv_b, q_b, k_b, vt_b);

  attn_fused2<<<512, 256, 0, stream>>>(q_b, k_b, vt_b, pout, ctx_b);

  gemm_part<<<dim3(2, 32, 4), 256, 0, stream>>>(ctx_b, dw_bf, 2048, 512, parts_d);
  reduce_ln<<<1024, 256, 0, stream>>>(parts_d, db, xn_f, ln2g, ln2b, x1_f, m_b);

  gemm_fc1<<<dim3(8, 32), 256, 0, stream>>>(m_b, f1_bf, f1b, h_b);

  gemm_part<<<dim3(2, 32, 4), 256, 0, stream>>>(h_b, f2_bf, 1024, 256, parts_f);
  reduce4<<<1024, 256, 0, stream>>>(parts_f, f2b, x1_f, out0);
}